// Round 7
// baseline (500.026 us; speedup 1.0000x reference)
//
#include <hip/hip_runtime.h>
#include <cmath>

// ---------------------------------------------------------------------------
// OHDeltaProductSSM: u(8,2048,1024) -> out(8,2048,1024), fp32.
// Round 7: scanB2 re-decomposed. The 8-block version is bounded by per-CU
// L2/L3 fill BW (64KB/iter into one CU ~0.45us floor; measured 1.19us/iter,
// 76us total). New scanB2x: 32 blocks = 8 batches x 4 row-groups; each block
// owns 32 rows (16KB M-slice/iter). Cross-block h exchange through hstart
// itself + device-scope flag sync (rocPRIM decoupled-lookback pattern:
// store -> threadfence -> barrier -> release atomicAdd; acquire poll ->
// barrier -> read; h addresses are fresh each iteration so no stale-cache
// hazard). M loads issued before the poll so latency overlaps the spin.
// Summation structure identical to old scanB2 -> bitwise-identical h.
// Flags zeroed by scanB0 (earlier in stream, every launch).
// Round 6 (kept): scanB1 round-2-verified shape; standalone scanB0.
// Round 3 (kept): LCH=32/512 chunks; 2-phase dbuf MFMA gemms.
// Round 2 (kept): gemmC = bf16 MFMA 3-pass split. Round 1: gemmA 2-pass split.
// Tiled operand layout: tile (rowblk, kt) = 128x32 bf16, 8 KB contiguous;
//   elem (r,k): g=k>>2, p=g&3, h=g>>2, s'=((p^((r>>2)&3))<<1)|h,
//   index = r*32 + s'*4 + (k&3); identical permutation on A and B.
// MFMA facts: A row = lane&15, B col = lane&15, D: col=lane&15,
// row = 4*(lane>>4)+reg  [guide m89/m91].
// ---------------------------------------------------------------------------

#define NTOK 16384
#define TT 2048
#define BB 8
#define DM 1024
#define FS 520
#define CH 64          // chunks per batch
#define LCH 32         // tokens per chunk
#define NCH 512        // total chunks
#define NW 448
#define NWP 512

typedef short bf16x8 __attribute__((ext_vector_type(8)));
typedef float f32x4 __attribute__((ext_vector_type(4)));

#define GLOAD_LDS16(g, l)                                          \
  __builtin_amdgcn_global_load_lds(                                \
      (const __attribute__((address_space(1))) void*)(g),          \
      (__attribute__((address_space(3))) void*)(l), 16, 0, 0)

__global__ __launch_bounds__(256) void packW(
    const float* __restrict__ W_A, const float* __restrict__ b_A,
    const float* __restrict__ W_k, const float* __restrict__ b_k,
    const float* __restrict__ b_beta,
    const float* __restrict__ B_w, const float* __restrict__ B_b,
    float* __restrict__ Wp, float* __restrict__ bias) {
  int r = blockIdx.x;          // 0..447
  int tid = threadIdx.x;
  const float* src;
  float bv;
  if (r < 64)       { src = W_A + (size_t)r * DM;         bv = b_A[r]; }
  else if (r < 320) { src = W_k + (size_t)(r - 64) * DM;  bv = b_k[r - 64]; }
  else              { src = B_w + (size_t)(r - 320) * DM; bv = B_b[r - 320]; }
  ((float4*)(Wp + (size_t)r * DM))[tid] = ((const float4*)src)[tid];
  if (tid == 0) bias[r] = bv;
  if (r == 0 && tid < 2) bias[448 + tid] = b_beta[tid];
}

__device__ inline unsigned short bf16_rne(float x) {
  unsigned b = __float_as_uint(x);
  b += 0x7FFFu + ((b >> 16) & 1u);
  return (unsigned short)(b >> 16);
}

__device__ inline void split_bf16(float x, unsigned short& h, unsigned short& l) {
  unsigned b = __float_as_uint(x);
  h = (unsigned short)(b >> 16);                       // truncated high part
  float rem = x - __uint_as_float(b & 0xFFFF0000u);    // exact remainder
  l = bf16_rne(rem);
}

// u fp32 -> u_hi/u_lo bf16, tiled (mb,kt) 128x32, swizzled granules.
__global__ __launch_bounds__(256) void convertU(
    const float* __restrict__ u, unsigned short* __restrict__ uh,
    unsigned short* __restrict__ ul) {
  int gid = blockIdx.x * 256 + threadIdx.x;
  int m = gid >> 8;          // token row
  int g = gid & 255;         // granule along k
  float4 v = *(const float4*)(u + (size_t)m * DM + g * 4);
  int kt = g >> 3, gg = g & 7;
  int p = gg & 3, h = gg >> 2;
  int mr = m & 127, mb = m >> 7;
  int pp = p ^ ((mr >> 2) & 3);
  size_t dst = ((size_t)(mb * 32 + kt)) * 4096 + mr * 32 + ((pp << 1) | h) * 4;
  ushort4 hi, lo;
  split_bf16(v.x, hi.x, lo.x);
  split_bf16(v.y, hi.y, lo.y);
  split_bf16(v.z, hi.z, lo.z);
  split_bf16(v.w, hi.w, lo.w);
  *(ushort4*)(uh + dst) = hi;
  *(ushort4*)(ul + dst) = lo;
}

// Wp fp32 (448 rows) -> Wb bf16 tiled (nb,kt) 128x32, rows 448..511 zero.
__global__ __launch_bounds__(256) void convertW(
    const float* __restrict__ Wp, unsigned short* __restrict__ Wb) {
  int gid = blockIdx.x * 256 + threadIdx.x;
  int n = gid >> 8, g = gid & 255;
  int kt = g >> 3, gg = g & 7;
  int p = gg & 3, h = gg >> 2;
  int nr = n & 127, nb = n >> 7;
  int pp = p ^ ((nr >> 2) & 3);
  size_t dst = ((size_t)(nb * 32 + kt)) * 4096 + nr * 32 + ((pp << 1) | h) * 4;
  ushort4 hv = make_ushort4(0, 0, 0, 0);
  if (n < NW) {
    float4 v = *(const float4*)(Wp + (size_t)n * DM + g * 4);
    hv.x = bf16_rne(v.x); hv.y = bf16_rne(v.y);
    hv.z = bf16_rne(v.z); hv.w = bf16_rne(v.w);
  }
  *(ushort4*)(Wb + dst) = hv;
}

// Cm[1024][128] fp32 -> C_hi/C_lo bf16 tiled (nb,kt).
__global__ __launch_bounds__(256) void convertC(
    const float* __restrict__ Cm, unsigned short* __restrict__ Chp,
    unsigned short* __restrict__ Clp) {
  int gid = blockIdx.x * 256 + threadIdx.x;   // 32768 total
  int d = gid >> 5;          // 0..1023
  int g = gid & 31;          // granule along 128
  float4 v = *(const float4*)(Cm + (size_t)d * 128 + g * 4);
  int kt = g >> 3, gg = g & 7;
  int p = gg & 3, h = gg >> 2;
  int nr = d & 127, nb = d >> 7;
  int pp = p ^ ((nr >> 2) & 3);
  size_t dst = ((size_t)(nb * 4 + kt)) * 4096 + nr * 32 + ((pp << 1) | h) * 4;
  ushort4 hi, lo;
  split_bf16(v.x, hi.x, lo.x);
  split_bf16(v.y, hi.y, lo.y);
  split_bf16(v.z, hi.z, lo.z);
  split_bf16(v.w, hi.w, lo.w);
  *(ushort4*)(Chp + dst) = hi;
  *(ushort4*)(Clp + dst) = lo;
}

// Feat[0..512) = (u_hi + u_lo) . Wb^T via MFMA. 128x128 tile, BK=32,
// 2-phase double-buffered LDS, one barrier per K-step.
__global__ __launch_bounds__(256) void gemmA_mfma(
    const unsigned short* __restrict__ uh, const unsigned short* __restrict__ ul,
    const unsigned short* __restrict__ Wb, float* __restrict__ Feat) {
  __shared__ __align__(16) unsigned short As[8192];
  __shared__ __align__(16) unsigned short Bs[8192];
  const int tid = threadIdx.x;
  const int wv = tid >> 6, ln = tid & 63;
  const int lr = ln & 15, G = ln >> 4;
  const int wm = wv >> 1, wn = wv & 1;
  const int x = G ^ (lr >> 2);
  f32x4 acc[4][4];
#pragma unroll
  for (int i = 0; i < 4; ++i)
#pragma unroll
    for (int j = 0; j < 4; ++j) acc[i][j] = (f32x4){0.f, 0.f, 0.f, 0.f};

  const size_t aBase = (size_t)blockIdx.x * 32 * 4096;
  const size_t bBase = (size_t)blockIdx.y * 32 * 4096;
  const int so = wv * 512 + ln * 8;
  const int ld = wv * 512;

  auto stage = [&](int step, int buf) {
    const unsigned short* pa = (step < 32) ? uh : ul;
    const int kt = step & 31;
    const unsigned short* ga = pa + aBase + (size_t)kt * 4096;
    const unsigned short* gb = Wb + bBase + (size_t)kt * 4096;
    unsigned short* A = As + buf * 4096;
    unsigned short* B = Bs + buf * 4096;
    GLOAD_LDS16(ga + so,        A + ld);
    GLOAD_LDS16(ga + 2048 + so, A + 2048 + ld);
    GLOAD_LDS16(gb + so,        B + ld);
    GLOAD_LDS16(gb + 2048 + so, B + 2048 + ld);
  };

  stage(0, 0);
  __syncthreads();
  for (int s = 0; s < 64; ++s) {
    const int cur = s & 1;
    if (s + 1 < 64) stage(s + 1, cur ^ 1);
    bf16x8 af[4], bfr[4];
    const char* Ab = (const char*)(As + cur * 4096) + ((wm * 64 + lr) << 6) + (x << 4);
    const char* Bb = (const char*)(Bs + cur * 4096) + ((wn * 64 + lr) << 6) + (x << 4);
#pragma unroll
    for (int i = 0; i < 4; ++i) {
      af[i]  = *(const bf16x8*)(Ab + i * 1024);
      bfr[i] = *(const bf16x8*)(Bb + i * 1024);
    }
#pragma unroll
    for (int i = 0; i < 4; ++i)
#pragma unroll
      for (int j = 0; j < 4; ++j)
        acc[i][j] = __builtin_amdgcn_mfma_f32_16x16x32_bf16(
            af[i], bfr[j], acc[i][j], 0, 0, 0);
    __syncthreads();
  }
  const int row0 = (blockIdx.x << 7) + wm * 64 + (G << 2);
  const int col0 = (blockIdx.y << 7) + wn * 64 + lr;
  float* fb = Feat + (size_t)row0 * FS + col0;
#pragma unroll
  for (int i = 0; i < 4; ++i)
#pragma unroll
    for (int j = 0; j < 4; ++j) {
      float* d = fb + (size_t)(i * 16) * FS + j * 16;
#pragma unroll
      for (int r = 0; r < 4; ++r) d[(size_t)r * FS] = acc[i][j][r];
    }
}

// out = hs.C^T + u*D via MFMA, 3 passes (hh, lh, hl), 2-phase dbuf.
__global__ __launch_bounds__(256) void gemmC_mfma(
    const unsigned short* __restrict__ hsh, const unsigned short* __restrict__ hsl,
    const unsigned short* __restrict__ Chp, const unsigned short* __restrict__ Clp,
    const float* __restrict__ u, const float* __restrict__ Dv,
    float* __restrict__ out) {
  __shared__ __align__(16) unsigned short As[8192];
  __shared__ __align__(16) unsigned short Bs[8192];
  const int tid = threadIdx.x;
  const int wv = tid >> 6, ln = tid & 63;
  const int lr = ln & 15, G = ln >> 4;
  const int wm = wv >> 1, wn = wv & 1;
  const int x = G ^ (lr >> 2);
  f32x4 acc[4][4];
#pragma unroll
  for (int i = 0; i < 4; ++i)
#pragma unroll
    for (int j = 0; j < 4; ++j) acc[i][j] = (f32x4){0.f, 0.f, 0.f, 0.f};

  const size_t aBase = (size_t)blockIdx.x * 4 * 4096;
  const size_t bBase = (size_t)blockIdx.y * 4 * 4096;
  const int so = wv * 512 + ln * 8;
  const int ld = wv * 512;

  auto stage = [&](int step, int buf) {
    const int pass = step >> 2, kt = step & 3;
    const unsigned short* pa = (pass == 1) ? hsl : hsh;
    const unsigned short* pb = (pass == 2) ? Clp : Chp;
    const unsigned short* ga = pa + aBase + (size_t)kt * 4096;
    const unsigned short* gb = pb + bBase + (size_t)kt * 4096;
    unsigned short* A = As + buf * 4096;
    unsigned short* B = Bs + buf * 4096;
    GLOAD_LDS16(ga + so,        A + ld);
    GLOAD_LDS16(ga + 2048 + so, A + 2048 + ld);
    GLOAD_LDS16(gb + so,        B + ld);
    GLOAD_LDS16(gb + 2048 + so, B + 2048 + ld);
  };

  stage(0, 0);
  __syncthreads();
  for (int s = 0; s < 12; ++s) {
    const int cur = s & 1;
    if (s + 1 < 12) stage(s + 1, cur ^ 1);
    bf16x8 af[4], bfr[4];
    const char* Ab = (const char*)(As + cur * 4096) + ((wm * 64 + lr) << 6) + (x << 4);
    const char* Bb = (const char*)(Bs + cur * 4096) + ((wn * 64 + lr) << 6) + (x << 4);
#pragma unroll
    for (int i = 0; i < 4; ++i) {
      af[i]  = *(const bf16x8*)(Ab + i * 1024);
      bfr[i] = *(const bf16x8*)(Bb + i * 1024);
    }
#pragma unroll
    for (int i = 0; i < 4; ++i)
#pragma unroll
      for (int j = 0; j < 4; ++j)
        acc[i][j] = __builtin_amdgcn_mfma_f32_16x16x32_bf16(
            af[i], bfr[j], acc[i][j], 0, 0, 0);
    __syncthreads();
  }
  const int row0 = (blockIdx.x << 7) + wm * 64 + (G << 2);
  const int col0 = (blockIdx.y << 7) + wn * 64 + lr;
#pragma unroll
  for (int j = 0; j < 4; ++j) {
    float dv = Dv[col0 + j * 16];
#pragma unroll
    for (int i = 0; i < 4; ++i) {
#pragma unroll
      for (int r = 0; r < 4; ++r) {
        size_t off = (size_t)(row0 + i * 16 + r) * DM + col0 + j * 16;
        out[off] = fmaf(u[off], dv, acc[i][j][r]);
      }
    }
  }
}

__device__ inline float wave_sum(float v) {
#pragma unroll
  for (int off = 32; off > 0; off >>= 1) v += __shfl_xor(v, off, 64);
  return v;
}

// per-token nonlinearity, one wave per token, in-place in Feat
__global__ __launch_bounds__(64) void postA(float* __restrict__ Feat,
                                            const float* __restrict__ bias,
                                            const float* __restrict__ u,
                                            const float* __restrict__ Wb) {
  const int t = blockIdx.x, lane = threadIdx.x;
  float* f = Feat + (size_t)t * FS;
  float s0 = 0.f, s1 = 0.f;
#pragma unroll
  for (int j = 0; j < 4; ++j) {
    float4 uv = *(const float4*)(u + (size_t)t * DM + j * 256 + lane * 4);
    float4 w0 = *(const float4*)(Wb + j * 256 + lane * 4);
    float4 w1 = *(const float4*)(Wb + DM + j * 256 + lane * 4);
    s0 = fmaf(uv.x, w0.x, s0); s0 = fmaf(uv.y, w0.y, s0);
    s0 = fmaf(uv.z, w0.z, s0); s0 = fmaf(uv.w, w0.w, s0);
    s1 = fmaf(uv.x, w1.x, s1); s1 = fmaf(uv.y, w1.y, s1);
    s1 = fmaf(uv.z, w1.z, s1); s1 = fmaf(uv.w, w1.w, s1);
  }
  s0 = wave_sum(s0); s1 = wave_sum(s1);
  float a = f[lane] + bias[lane];
  a = fminf(fmaxf(a, 0.f), 100.f);
  float S = 1.f / (1.f + 0.01f * a);
  f[lane] = S;
  f[448 + lane] = 0.1f * a * S;
  float k10 = f[64 + lane] + bias[64 + lane];
  float k11 = f[128 + lane] + bias[128 + lane];
  float n1 = wave_sum(k10 * k10 + k11 * k11);
  float inv1 = 1.f / fmaxf(sqrtf(n1), 1e-12f);
  k10 *= inv1; k11 *= inv1;
  f[64 + lane] = k10; f[128 + lane] = k11;
  float k20 = f[192 + lane] + bias[192 + lane];
  float k21 = f[256 + lane] + bias[256 + lane];
  float n2 = wave_sum(k20 * k20 + k21 * k21);
  float inv2 = 1.f / fmaxf(sqrtf(n2), 1e-12f);
  k20 *= inv2; k21 *= inv2;
  f[192 + lane] = k20; f[256 + lane] = k21;
  float c12 = wave_sum(k10 * k20 + k11 * k21);
  if (lane == 0) {
    f[512] = 2.f / (1.f + expf(-(s0 + bias[448])));
    f[513] = 2.f / (1.f + expf(-(s1 + bias[449])));
    f[514] = c12;
  }
  f[320 + lane] += bias[320 + lane];
  f[384 + lane] += bias[384 + lane];
}

// chunk transition matrices. Round-2-verified shape: 512 threads,
// col = tid>>2 (0..127), quarter q = tid&3, 16 elems/thread, VGPR=64.
__global__ __launch_bounds__(512, 2) void scanB1(
    const float* __restrict__ Feat, float* __restrict__ Mc) {
  const int cid = blockIdx.x;              // 0..511 = b*64 + chunk
  const int t0 = (cid >> 6) * TT + (cid & 63) * LCH;
  const int tid = threadIdx.x;
  const int col = tid >> 2, q = tid & 3;
  const int i0 = q * 16;
  __shared__ float fb[2][4 * FS];
  float mz[16], my[16];
#pragma unroll
  for (int j = 0; j < 16; ++j) {
    mz[j] = (i0 + j == col) ? 1.f : 0.f;
    my[j] = (64 + i0 + j == col) ? 1.f : 0.f;
  }
  {
    const float4* src = (const float4*)(Feat + (size_t)t0 * FS);
    for (int v = tid; v < FS; v += 512) ((float4*)fb[0])[v] = src[v];
  }
  __syncthreads();
  for (int g = 0; g < LCH / 4; ++g) {
    const int cur = g & 1;
    float4 pf0, pf1;
    const bool has2 = tid < (FS - 512);
    if (g < LCH / 4 - 1) {
      const float4* src = (const float4*)(Feat + (size_t)(t0 + (g + 1) * 4) * FS);
      pf0 = src[tid];
      if (has2) pf1 = src[tid + 512];
    }
#pragma unroll
    for (int s = 0; s < 4; ++s) {
      const float* f = fb[cur] + s * FS;
      float sj[16], cj[16], k1z[16], k1y[16], k2z[16], k2y[16];
#pragma unroll
      for (int v = 0; v < 4; ++v) {
        *(float4*)&sj[4 * v]  = *(const float4*)(f + i0 + 4 * v);
        *(float4*)&cj[4 * v]  = *(const float4*)(f + 448 + i0 + 4 * v);
        *(float4*)&k1z[4 * v] = *(const float4*)(f + 64 + i0 + 4 * v);
        *(float4*)&k1y[4 * v] = *(const float4*)(f + 128 + i0 + 4 * v);
        *(float4*)&k2z[4 * v] = *(const float4*)(f + 192 + i0 + 4 * v);
        *(float4*)&k2y[4 * v] = *(const float4*)(f + 256 + i0 + 4 * v);
      }
      float4 sc = *(const float4*)(f + 512);   // b1, b2, c12, pad
      float p = 0.f, r2 = 0.f;
#pragma unroll
      for (int j = 0; j < 16; ++j) {
        float s0 = sj[j], c1 = cj[j];
        float z = mz[j], y = my[j];
        float sz = s0 * z;
        z = fmaf(-c1, y, sz);
        y = fmaf(s0, y, 0.1f * sz);
        mz[j] = z; my[j] = y;
        p  = fmaf(k1z[j], z, p);  p  = fmaf(k1y[j], y, p);
        r2 = fmaf(k2z[j], z, r2); r2 = fmaf(k2y[j], y, r2);
      }
      p  += __shfl_xor(p, 1, 64);  p  += __shfl_xor(p, 2, 64);
      r2 += __shfl_xor(r2, 1, 64); r2 += __shfl_xor(r2, 2, 64);
      float e1 = sc.x * p;
      float e2 = sc.y * fmaf(-sc.z, e1, r2);
#pragma unroll
      for (int j = 0; j < 16; ++j) {
        float z = fmaf(-e1, k1z[j], mz[j]);
        mz[j] = fmaf(-e2, k2z[j], z);
        float y = fmaf(-e1, k1y[j], my[j]);
        my[j] = fmaf(-e2, k2y[j], y);
      }
    }
    if (g < LCH / 4 - 1) {
      ((float4*)fb[1 - cur])[tid] = pf0;
      if (has2) ((float4*)fb[1 - cur])[tid + 512] = pf1;
    }
    __syncthreads();
  }
  float* dst = Mc + ((size_t)cid * 128 + col) * 128;
#pragma unroll
  for (int v = 0; v < 4; ++v)
    *(float4*)(dst + i0 + 4 * v) = *(float4*)&mz[4 * v];
#pragma unroll
  for (int v = 0; v < 4; ++v)
    *(float4*)(dst + 64 + i0 + 4 * v) = *(float4*)&my[4 * v];
}

// offset column d_c: affine replay from h=0, one wave per chunk.
// block 0 also zeroes the scanB2x flags (runs before scanB2x in-stream).
__global__ __launch_bounds__(64) void scanB0(
    const float* __restrict__ Feat, float* __restrict__ dc,
    int* __restrict__ flags) {
  const int cid = blockIdx.x;
  const int lane = threadIdx.x;
  if (cid == 0) {
    for (int i = lane; i < 512; i += 64) flags[i] = 0;
  }
  float z = 0.f, y = 0.f;
  const int t0 = (cid >> 6) * TT + (cid & 63) * LCH;
  for (int t = t0; t < t0 + LCH; ++t) {
    const float* __restrict__ f = Feat + (size_t)t * FS;
    float s = f[lane], c1 = f[448 + lane];
    float k1z = f[64 + lane], k1y = f[128 + lane];
    float k2z = f[192 + lane], k2y = f[256 + lane];
    float bz = f[320 + lane], by = f[384 + lane];
    float b1 = f[512], b2 = f[513], c12 = f[514];
    float sz = s * z;
    float zn = fmaf(-c1, y, sz);
    float yn = fmaf(s, y, 0.1f * sz);
    float p = fmaf(k1y, yn, k1z * zn);
    float qq = fmaf(k2y, yn, k2z * zn);
#pragma unroll
    for (int off = 32; off > 0; off >>= 1) {
      p += __shfl_xor(p, off, 64);
      qq += __shfl_xor(qq, off, 64);
    }
    float e1 = b1 * p;
    float d2 = fmaf(-c12, e1, qq);
    float e2 = b2 * d2;
    z = fmaf(-e1, k1z, zn); z = fmaf(-e2, k2z, z); z += bz;
    y = fmaf(-e1, k1y, yn); y = fmaf(-e2, k2y, y); y += by;
  }
  dc[(size_t)cid * 128 + lane] = z;
  dc[(size_t)cid * 128 + 64 + lane] = y;
}

// sequential chunk combine, multi-block: 32 blocks = 8 batches x 4 row
// groups of 32 rows. h exchanged through hstart (global) with device-scope
// flag sync per iteration. Summation structure identical to the old
// scanB2 (8 groups of 16-FMA chains + d) -> bitwise-identical h.
__global__ __launch_bounds__(256) void scanB2x(
    const float* __restrict__ Mc, const float* __restrict__ dc,
    float* __restrict__ hstart, int* __restrict__ flags) {
  const int bid = blockIdx.x;            // 0..31
  const int b = bid >> 2, g = bid & 3;   // batch, row-group
  const int tid = threadIdx.x;
  const int s = tid >> 5, r = tid & 31;  // col-segment 0..7, row-in-group
  const int R = g * 32 + r;              // owned row for loads
  __shared__ float dl[CH][32];
  __shared__ float red[8][32];
  __shared__ float hcur[128];
  // preload d slice for own rows, all chunks (8 KB)
  for (int idx = tid; idx < CH * 32; idx += 256) {
    int c = idx >> 5, rr = idx & 31;
    dl[c][rr] = dc[(size_t)(b * CH + c) * 128 + g * 32 + rr];
  }
  if (tid < 32) hstart[(size_t)(b * CH) * 128 + g * 32 + tid] = 0.f;
  if (tid < 128) hcur[tid] = 0.f;
  __syncthreads();

  for (int c = 0; c < CH; ++c) {
    // issue M-slice loads before the flag poll (latency overlaps the spin)
    const float* Mp = Mc + ((size_t)(b * CH + c) * 128 + s * 16) * 128 + R;
    float m[16];
#pragma unroll
    for (int j = 0; j < 16; ++j) m[j] = Mp[(size_t)j * 128];
    if (c > 0) {
      if (tid == 0) {
        int guard = 0;
        while (__hip_atomic_load(&flags[b * 64 + c], __ATOMIC_ACQUIRE,
                                 __HIP_MEMORY_SCOPE_AGENT) < 4) {
          __builtin_amdgcn_s_sleep(1);
          if (++guard > (1 << 26)) break;   // pathological-hang escape
        }
      }
      __syncthreads();
      if (tid < 128) hcur[tid] = hstart[(size_t)(b * CH + c) * 128 + tid];
      __syncthreads();
    }
    float acc = 0.f;
#pragma unroll
    for (int j = 0; j < 16; ++j) acc = fmaf(m[j], hcur[s * 16 + j], acc);
    red[s][r] = acc;
    __syncthreads();
    if (c + 1 < CH) {
      if (tid < 32) {
        float sum = dl[c][tid];
#pragma unroll
        for (int k = 0; k < 8; ++k) sum += red[k][tid];
        hstart[(size_t)(b * CH + c + 1) * 128 + g * 32 + tid] = sum;
        __threadfence();
      }
      __syncthreads();
      if (tid == 0)
        __hip_atomic_fetch_add(&flags[b * 64 + c + 1], 1, __ATOMIC_RELEASE,
                               __HIP_MEMORY_SCOPE_AGENT);
    }
  }
}

// replay within chunk from h_start, one wave per chunk; write split bf16 hs
// in the tiled swizzled layout for gemmC_mfma.
__global__ __launch_bounds__(64) void scanB3(
    const float* __restrict__ Feat, const float* __restrict__ hstart,
    unsigned short* __restrict__ hsh, unsigned short* __restrict__ hsl) {
  const int cid = blockIdx.x;
  const int lane = threadIdx.x;
  float z = hstart[(size_t)cid * 128 + lane];
  float y = hstart[(size_t)cid * 128 + 64 + lane];
  const int t0 = (cid >> 6) * TT + (cid & 63) * LCH;
  const int ktz = lane >> 5, kkz = lane & 31;
  const int kty = (64 + lane) >> 5;
  const int pz = (kkz >> 2) & 3, hz = kkz >> 4;
  const int lowz = kkz & 3;
  for (int t = t0; t < t0 + LCH; ++t) {
    const float* __restrict__ f = Feat + (size_t)t * FS;
    float s = f[lane], c1 = f[448 + lane];
    float k1z = f[64 + lane], k1y = f[128 + lane];
    float k2z = f[192 + lane], k2y = f[256 + lane];
    float bz = f[320 + lane], by = f[384 + lane];
    float b1 = f[512], b2 = f[513], c12 = f[514];
    float sz = s * z;
    float zn = fmaf(-c1, y, sz);
    float yn = fmaf(s, y, 0.1f * sz);
    float p = fmaf(k1y, yn, k1z * zn);
    float qq = fmaf(k2y, yn, k2z * zn);
#pragma unroll
    for (int off = 32; off > 0; off >>= 1) {
      p += __shfl_xor(p, off, 64);
      qq += __shfl_xor(qq, off, 64);
    }
    float e1 = b1 * p;
    float d2 = fmaf(-c12, e1, qq);
    float e2 = b2 * d2;
    zn = fmaf(-e1, k1z, zn); zn = fmaf(-e2, k2z, zn); zn += bz;
    yn = fmaf(-e1, k1y, yn); yn = fmaf(-e2, k2y, yn); yn += by;
    {
      const int mb = t >> 7, mr = t & 127;
      const int xr = (mr >> 2) & 3;
      size_t idxz = ((size_t)(mb * 4 + ktz)) * 4096 + mr * 32 +
                    ((((pz ^ xr) << 1) | hz)) * 4 + lowz;
      size_t idxy = ((size_t)(mb * 4 + kty)) * 4096 + mr * 32 +
                    ((((pz ^ xr) << 1) | hz)) * 4 + lowz;
      unsigned short hi, lo;
      split_bf16(zn, hi, lo);
      hsh[idxz] = hi; hsl[idxz] = lo;
      split_bf16(yn, hi, lo);
      hsh[idxy] = hi; hsl[idxy] = lo;
    }
    z = zn; y = yn;
  }
}

extern "C" void kernel_launch(void* const* d_in, const int* in_sizes, int n_in,
                              void* d_out, int out_size, void* d_ws, size_t ws_size,
                              hipStream_t stream) {
  const float* u      = (const float*)d_in[0];
  const float* W_A    = (const float*)d_in[1];
  const float* b_A    = (const float*)d_in[2];
  const float* W_k    = (const float*)d_in[3];
  const float* b_k    = (const float*)d_in[4];
  const float* W_beta = (const float*)d_in[5];
  const float* b_beta = (const float*)d_in[6];
  const float* B_w    = (const float*)d_in[7];
  const float* B_b    = (const float*)d_in[8];
  const float* Cm     = (const float*)d_in[9];
  const float* Dv     = (const float*)d_in[10];
  float* out = (float*)d_out;
  char* ws = (char*)d_ws;
  // workspace carve-up (~105.4 MB):
  //  Wp    0          1,835,008
  //  Wb    1,835,008  1,048,576
  //  bias  4,194,304  4,096
  //  Feat  4,198,400  34,078,720           -> ends 38,277,120
  //  uh    38,277,120 33,554,432  [dead after gemmA]
  //  Mc    38,277,120 33,554,432  (512*128*128*4, overlays uh)
  //  ul    71,831,552 33,554,432  [dead after gemmA pass 2]
  //   hsh  71,831,552 4,194,304   (overlays ul)
  //   hsl  76,025,856 4,194,304
  //   Chp  80,220,160 262,144
  //   Clp  80,482,304 262,144
  //   dcv  80,744,448 262,144
  //   hst  81,006,592 262,144
  //   flg  81,268,736 2,048       -> ends 81,270,784 (< ul end)
  float* Wp     = (float*)(ws);
  unsigned short* Wb = (unsigned short*)(ws + 1835008);
  float* bias   = (float*)(ws + 4194304);
  float* Feat   = (float*)(ws + 4198400);
  unsigned short* uh = (unsigned short*)(ws + 38277120);
  float* Mc     = (float*)(ws + 38277120);
  unsigned short* ul = (unsigned short*)(ws + 71831552);
  unsigned short* hsh = (unsigned short*)(ws + 71831552);
  unsigned short* hsl = (unsigned short*)(ws + 76025856);
  unsigned short* Chp = (unsigned short*)(ws + 80220160);
  unsigned short* Clp = (unsigned short*)(ws + 80482304);
  float* dcv    = (float*)(ws + 80744448);
  float* hstart = (float*)(ws + 81006592);
  int* flags    = (int*)(ws + 81268736);

  packW<<<dim3(448), dim3(256), 0, stream>>>(W_A, b_A, W_k, b_k, b_beta,
                                             B_w, B_b, Wp, bias);
  convertW<<<dim3(512), dim3(256), 0, stream>>>(Wp, Wb);
  convertU<<<dim3(16384), dim3(256), 0, stream>>>(u, uh, ul);
  gemmA_mfma<<<dim3(128, 4), dim3(256), 0, stream>>>(uh, ul, Wb, Feat);
  convertC<<<dim3(128), dim3(256), 0, stream>>>(Cm, Chp, Clp);
  postA<<<dim3(16384), dim3(64), 0, stream>>>(Feat, bias, u, W_beta);
  scanB1<<<dim3(NCH), dim3(512), 0, stream>>>(Feat, Mc);
  scanB0<<<dim3(NCH), dim3(64), 0, stream>>>(Feat, dcv, flags);
  scanB2x<<<dim3(32), dim3(256), 0, stream>>>(Mc, dcv, hstart, flags);
  scanB3<<<dim3(NCH), dim3(64), 0, stream>>>(Feat, hstart, hsh, hsl);
  gemmC_mfma<<<dim3(128, 8), dim3(256), 0, stream>>>(hsh, hsl, Chp, Clp,
                                                     u, Dv, out);
}

// Round 8
// 401.563 us; speedup vs baseline: 1.2452x; 1.2452x over previous
//
#include <hip/hip_runtime.h>
#include <cmath>

// ---------------------------------------------------------------------------
// OHDeltaProductSSM: u(8,2048,1024) -> out(8,2048,1024), fp32.
// Round 8:
//  - scanB2: register double-buffer + raw lgkm-only barriers, now under
//    __launch_bounds__(1024,1). R4's identical structure failed ONLY because
//    (1024,8) capped VGPR at 64 -> spill (WRITE 704KB). R6 measured the
//    (1024,1) body at VGPR=52, no spill. Prefetch (16 M-elems + d) issued at
//    iteration start, consumed after the 2nd barrier -> full-iteration
//    latency cover; RAW_BAR never drains vmcnt.
//    scanB2 ledger: R3 naive=68.5, R5 LDS-dbuf=76.4, R7 multi-block=158.9.
//  - packW eliminated: convertW reads W_A/W_k/B_w directly; its zero-pad
//    block 448 writes bias[450]. One fewer launch.
// Round 6 (kept): scanB1 round-2-verified shape (512thr, bounds(512,2));
// standalone scanB0. Round 3 (kept): LCH=32/512 chunks; 2-phase dbuf MFMA
// gemms. Round 2: gemmC 3-pass split MFMA. Round 1: gemmA 2-pass split.
// Tiled operand layout: tile (rowblk, kt) = 128x32 bf16, 8 KB contiguous;
//   elem (r,k): g=k>>2, p=g&3, h=g>>2, s'=((p^((r>>2)&3))<<1)|h,
//   index = r*32 + s'*4 + (k&3); identical permutation on A and B.
// MFMA facts: A row = lane&15, B col = lane&15, D: col=lane&15,
// row = 4*(lane>>4)+reg  [guide m89/m91].
// ---------------------------------------------------------------------------

#define NTOK 16384
#define TT 2048
#define BB 8
#define DM 1024
#define FS 520
#define CH 64          // chunks per batch
#define LCH 32         // tokens per chunk
#define NCH 512        // total chunks
#define NW 448
#define NWP 512

typedef short bf16x8 __attribute__((ext_vector_type(8)));
typedef float f32x4 __attribute__((ext_vector_type(4)));

#define GLOAD_LDS16(g, l)                                          \
  __builtin_amdgcn_global_load_lds(                                \
      (const __attribute__((address_space(1))) void*)(g),          \
      (__attribute__((address_space(3))) void*)(l), 16, 0, 0)

// raw workgroup barrier that does NOT drain vmcnt (keeps global prefetches
// in flight). LDS ordering via lgkmcnt(0); sched_barrier fences both sides.
#define RAW_BAR() do {                                             \
    asm volatile("s_waitcnt lgkmcnt(0)" ::: "memory");             \
    __builtin_amdgcn_sched_barrier(0);                             \
    __builtin_amdgcn_s_barrier();                                  \
    __builtin_amdgcn_sched_barrier(0);                             \
  } while (0)

__device__ inline unsigned short bf16_rne(float x) {
  unsigned b = __float_as_uint(x);
  b += 0x7FFFu + ((b >> 16) & 1u);
  return (unsigned short)(b >> 16);
}

__device__ inline void split_bf16(float x, unsigned short& h, unsigned short& l) {
  unsigned b = __float_as_uint(x);
  h = (unsigned short)(b >> 16);                       // truncated high part
  float rem = x - __uint_as_float(b & 0xFFFF0000u);    // exact remainder
  l = bf16_rne(rem);
}

// u fp32 -> u_hi/u_lo bf16, tiled (mb,kt) 128x32, swizzled granules.
__global__ __launch_bounds__(256) void convertU(
    const float* __restrict__ u, unsigned short* __restrict__ uh,
    unsigned short* __restrict__ ul) {
  int gid = blockIdx.x * 256 + threadIdx.x;
  int m = gid >> 8;          // token row
  int g = gid & 255;         // granule along k
  float4 v = *(const float4*)(u + (size_t)m * DM + g * 4);
  int kt = g >> 3, gg = g & 7;
  int p = gg & 3, h = gg >> 2;
  int mr = m & 127, mb = m >> 7;
  int pp = p ^ ((mr >> 2) & 3);
  size_t dst = ((size_t)(mb * 32 + kt)) * 4096 + mr * 32 + ((pp << 1) | h) * 4;
  ushort4 hi, lo;
  split_bf16(v.x, hi.x, lo.x);
  split_bf16(v.y, hi.y, lo.y);
  split_bf16(v.z, hi.z, lo.z);
  split_bf16(v.w, hi.w, lo.w);
  *(ushort4*)(uh + dst) = hi;
  *(ushort4*)(ul + dst) = lo;
}

// weights -> Wb bf16 tiled (nb,kt) 128x32, rows 448..511 zero. Reads the
// original W_A/W_k/B_w directly (packW eliminated). Block 448 writes bias.
__global__ __launch_bounds__(256) void convertW(
    const float* __restrict__ W_A, const float* __restrict__ W_k,
    const float* __restrict__ B_w, const float* __restrict__ b_A,
    const float* __restrict__ b_k, const float* __restrict__ B_b,
    const float* __restrict__ b_beta, unsigned short* __restrict__ Wb,
    float* __restrict__ bias) {
  int n = blockIdx.x;        // 0..511 (row)
  int g = threadIdx.x;       // granule along k
  int kt = g >> 3, gg = g & 7;
  int p = gg & 3, h = gg >> 2;
  int nr = n & 127, nb = n >> 7;
  int pp = p ^ ((nr >> 2) & 3);
  size_t dst = ((size_t)(nb * 32 + kt)) * 4096 + nr * 32 + ((pp << 1) | h) * 4;
  ushort4 hv = make_ushort4(0, 0, 0, 0);
  if (n < NW) {
    const float* src;
    if (n < 64)       src = W_A + (size_t)n * DM;
    else if (n < 320) src = W_k + (size_t)(n - 64) * DM;
    else              src = B_w + (size_t)(n - 320) * DM;
    float4 v = *(const float4*)(src + g * 4);
    hv.x = bf16_rne(v.x); hv.y = bf16_rne(v.y);
    hv.z = bf16_rne(v.z); hv.w = bf16_rne(v.w);
  }
  *(ushort4*)(Wb + dst) = hv;
  if (n == 448) {
    for (int i = threadIdx.x; i < 450; i += 256) {
      float bv;
      if (i < 64)       bv = b_A[i];
      else if (i < 320) bv = b_k[i - 64];
      else if (i < 448) bv = B_b[i - 320];
      else              bv = b_beta[i - 448];
      bias[i] = bv;
    }
  }
}

// Cm[1024][128] fp32 -> C_hi/C_lo bf16 tiled (nb,kt).
__global__ __launch_bounds__(256) void convertC(
    const float* __restrict__ Cm, unsigned short* __restrict__ Chp,
    unsigned short* __restrict__ Clp) {
  int gid = blockIdx.x * 256 + threadIdx.x;   // 32768 total
  int d = gid >> 5;          // 0..1023
  int g = gid & 31;          // granule along 128
  float4 v = *(const float4*)(Cm + (size_t)d * 128 + g * 4);
  int kt = g >> 3, gg = g & 7;
  int p = gg & 3, h = gg >> 2;
  int nr = d & 127, nb = d >> 7;
  int pp = p ^ ((nr >> 2) & 3);
  size_t dst = ((size_t)(nb * 4 + kt)) * 4096 + nr * 32 + ((pp << 1) | h) * 4;
  ushort4 hi, lo;
  split_bf16(v.x, hi.x, lo.x);
  split_bf16(v.y, hi.y, lo.y);
  split_bf16(v.z, hi.z, lo.z);
  split_bf16(v.w, hi.w, lo.w);
  *(ushort4*)(Chp + dst) = hi;
  *(ushort4*)(Clp + dst) = lo;
}

// Feat[0..512) = (u_hi + u_lo) . Wb^T via MFMA. 128x128 tile, BK=32,
// 2-phase double-buffered LDS, one barrier per K-step.
__global__ __launch_bounds__(256) void gemmA_mfma(
    const unsigned short* __restrict__ uh, const unsigned short* __restrict__ ul,
    const unsigned short* __restrict__ Wb, float* __restrict__ Feat) {
  __shared__ __align__(16) unsigned short As[8192];
  __shared__ __align__(16) unsigned short Bs[8192];
  const int tid = threadIdx.x;
  const int wv = tid >> 6, ln = tid & 63;
  const int lr = ln & 15, G = ln >> 4;
  const int wm = wv >> 1, wn = wv & 1;
  const int x = G ^ (lr >> 2);
  f32x4 acc[4][4];
#pragma unroll
  for (int i = 0; i < 4; ++i)
#pragma unroll
    for (int j = 0; j < 4; ++j) acc[i][j] = (f32x4){0.f, 0.f, 0.f, 0.f};

  const size_t aBase = (size_t)blockIdx.x * 32 * 4096;
  const size_t bBase = (size_t)blockIdx.y * 32 * 4096;
  const int so = wv * 512 + ln * 8;
  const int ld = wv * 512;

  auto stage = [&](int step, int buf) {
    const unsigned short* pa = (step < 32) ? uh : ul;
    const int kt = step & 31;
    const unsigned short* ga = pa + aBase + (size_t)kt * 4096;
    const unsigned short* gb = Wb + bBase + (size_t)kt * 4096;
    unsigned short* A = As + buf * 4096;
    unsigned short* B = Bs + buf * 4096;
    GLOAD_LDS16(ga + so,        A + ld);
    GLOAD_LDS16(ga + 2048 + so, A + 2048 + ld);
    GLOAD_LDS16(gb + so,        B + ld);
    GLOAD_LDS16(gb + 2048 + so, B + 2048 + ld);
  };

  stage(0, 0);
  __syncthreads();
  for (int s = 0; s < 64; ++s) {
    const int cur = s & 1;
    if (s + 1 < 64) stage(s + 1, cur ^ 1);
    bf16x8 af[4], bfr[4];
    const char* Ab = (const char*)(As + cur * 4096) + ((wm * 64 + lr) << 6) + (x << 4);
    const char* Bb = (const char*)(Bs + cur * 4096) + ((wn * 64 + lr) << 6) + (x << 4);
#pragma unroll
    for (int i = 0; i < 4; ++i) {
      af[i]  = *(const bf16x8*)(Ab + i * 1024);
      bfr[i] = *(const bf16x8*)(Bb + i * 1024);
    }
#pragma unroll
    for (int i = 0; i < 4; ++i)
#pragma unroll
      for (int j = 0; j < 4; ++j)
        acc[i][j] = __builtin_amdgcn_mfma_f32_16x16x32_bf16(
            af[i], bfr[j], acc[i][j], 0, 0, 0);
    __syncthreads();
  }
  const int row0 = (blockIdx.x << 7) + wm * 64 + (G << 2);
  const int col0 = (blockIdx.y << 7) + wn * 64 + lr;
  float* fb = Feat + (size_t)row0 * FS + col0;
#pragma unroll
  for (int i = 0; i < 4; ++i)
#pragma unroll
    for (int j = 0; j < 4; ++j) {
      float* d = fb + (size_t)(i * 16) * FS + j * 16;
#pragma unroll
      for (int r = 0; r < 4; ++r) d[(size_t)r * FS] = acc[i][j][r];
    }
}

// out = hs.C^T + u*D via MFMA, 3 passes (hh, lh, hl), 2-phase dbuf.
__global__ __launch_bounds__(256) void gemmC_mfma(
    const unsigned short* __restrict__ hsh, const unsigned short* __restrict__ hsl,
    const unsigned short* __restrict__ Chp, const unsigned short* __restrict__ Clp,
    const float* __restrict__ u, const float* __restrict__ Dv,
    float* __restrict__ out) {
  __shared__ __align__(16) unsigned short As[8192];
  __shared__ __align__(16) unsigned short Bs[8192];
  const int tid = threadIdx.x;
  const int wv = tid >> 6, ln = tid & 63;
  const int lr = ln & 15, G = ln >> 4;
  const int wm = wv >> 1, wn = wv & 1;
  const int x = G ^ (lr >> 2);
  f32x4 acc[4][4];
#pragma unroll
  for (int i = 0; i < 4; ++i)
#pragma unroll
    for (int j = 0; j < 4; ++j) acc[i][j] = (f32x4){0.f, 0.f, 0.f, 0.f};

  const size_t aBase = (size_t)blockIdx.x * 4 * 4096;
  const size_t bBase = (size_t)blockIdx.y * 4 * 4096;
  const int so = wv * 512 + ln * 8;
  const int ld = wv * 512;

  auto stage = [&](int step, int buf) {
    const int pass = step >> 2, kt = step & 3;
    const unsigned short* pa = (pass == 1) ? hsl : hsh;
    const unsigned short* pb = (pass == 2) ? Clp : Chp;
    const unsigned short* ga = pa + aBase + (size_t)kt * 4096;
    const unsigned short* gb = pb + bBase + (size_t)kt * 4096;
    unsigned short* A = As + buf * 4096;
    unsigned short* B = Bs + buf * 4096;
    GLOAD_LDS16(ga + so,        A + ld);
    GLOAD_LDS16(ga + 2048 + so, A + 2048 + ld);
    GLOAD_LDS16(gb + so,        B + ld);
    GLOAD_LDS16(gb + 2048 + so, B + 2048 + ld);
  };

  stage(0, 0);
  __syncthreads();
  for (int s = 0; s < 12; ++s) {
    const int cur = s & 1;
    if (s + 1 < 12) stage(s + 1, cur ^ 1);
    bf16x8 af[4], bfr[4];
    const char* Ab = (const char*)(As + cur * 4096) + ((wm * 64 + lr) << 6) + (x << 4);
    const char* Bb = (const char*)(Bs + cur * 4096) + ((wn * 64 + lr) << 6) + (x << 4);
#pragma unroll
    for (int i = 0; i < 4; ++i) {
      af[i]  = *(const bf16x8*)(Ab + i * 1024);
      bfr[i] = *(const bf16x8*)(Bb + i * 1024);
    }
#pragma unroll
    for (int i = 0; i < 4; ++i)
#pragma unroll
      for (int j = 0; j < 4; ++j)
        acc[i][j] = __builtin_amdgcn_mfma_f32_16x16x32_bf16(
            af[i], bfr[j], acc[i][j], 0, 0, 0);
    __syncthreads();
  }
  const int row0 = (blockIdx.x << 7) + wm * 64 + (G << 2);
  const int col0 = (blockIdx.y << 7) + wn * 64 + lr;
#pragma unroll
  for (int j = 0; j < 4; ++j) {
    float dv = Dv[col0 + j * 16];
#pragma unroll
    for (int i = 0; i < 4; ++i) {
#pragma unroll
      for (int r = 0; r < 4; ++r) {
        size_t off = (size_t)(row0 + i * 16 + r) * DM + col0 + j * 16;
        out[off] = fmaf(u[off], dv, acc[i][j][r]);
      }
    }
  }
}

__device__ inline float wave_sum(float v) {
#pragma unroll
  for (int off = 32; off > 0; off >>= 1) v += __shfl_xor(v, off, 64);
  return v;
}

// per-token nonlinearity, one wave per token, in-place in Feat
__global__ __launch_bounds__(64) void postA(float* __restrict__ Feat,
                                            const float* __restrict__ bias,
                                            const float* __restrict__ u,
                                            const float* __restrict__ Wb) {
  const int t = blockIdx.x, lane = threadIdx.x;
  float* f = Feat + (size_t)t * FS;
  float s0 = 0.f, s1 = 0.f;
#pragma unroll
  for (int j = 0; j < 4; ++j) {
    float4 uv = *(const float4*)(u + (size_t)t * DM + j * 256 + lane * 4);
    float4 w0 = *(const float4*)(Wb + j * 256 + lane * 4);
    float4 w1 = *(const float4*)(Wb + DM + j * 256 + lane * 4);
    s0 = fmaf(uv.x, w0.x, s0); s0 = fmaf(uv.y, w0.y, s0);
    s0 = fmaf(uv.z, w0.z, s0); s0 = fmaf(uv.w, w0.w, s0);
    s1 = fmaf(uv.x, w1.x, s1); s1 = fmaf(uv.y, w1.y, s1);
    s1 = fmaf(uv.z, w1.z, s1); s1 = fmaf(uv.w, w1.w, s1);
  }
  s0 = wave_sum(s0); s1 = wave_sum(s1);
  float a = f[lane] + bias[lane];
  a = fminf(fmaxf(a, 0.f), 100.f);
  float S = 1.f / (1.f + 0.01f * a);
  f[lane] = S;
  f[448 + lane] = 0.1f * a * S;
  float k10 = f[64 + lane] + bias[64 + lane];
  float k11 = f[128 + lane] + bias[128 + lane];
  float n1 = wave_sum(k10 * k10 + k11 * k11);
  float inv1 = 1.f / fmaxf(sqrtf(n1), 1e-12f);
  k10 *= inv1; k11 *= inv1;
  f[64 + lane] = k10; f[128 + lane] = k11;
  float k20 = f[192 + lane] + bias[192 + lane];
  float k21 = f[256 + lane] + bias[256 + lane];
  float n2 = wave_sum(k20 * k20 + k21 * k21);
  float inv2 = 1.f / fmaxf(sqrtf(n2), 1e-12f);
  k20 *= inv2; k21 *= inv2;
  f[192 + lane] = k20; f[256 + lane] = k21;
  float c12 = wave_sum(k10 * k20 + k11 * k21);
  if (lane == 0) {
    f[512] = 2.f / (1.f + expf(-(s0 + bias[448])));
    f[513] = 2.f / (1.f + expf(-(s1 + bias[449])));
    f[514] = c12;
  }
  f[320 + lane] += bias[320 + lane];
  f[384 + lane] += bias[384 + lane];
}

// chunk transition matrices. Round-2-verified shape: 512 threads,
// col = tid>>2 (0..127), quarter q = tid&3, 16 elems/thread, VGPR=64.
__global__ __launch_bounds__(512, 2) void scanB1(
    const float* __restrict__ Feat, float* __restrict__ Mc) {
  const int cid = blockIdx.x;              // 0..511 = b*64 + chunk
  const int t0 = (cid >> 6) * TT + (cid & 63) * LCH;
  const int tid = threadIdx.x;
  const int col = tid >> 2, q = tid & 3;
  const int i0 = q * 16;
  __shared__ float fb[2][4 * FS];
  float mz[16], my[16];
#pragma unroll
  for (int j = 0; j < 16; ++j) {
    mz[j] = (i0 + j == col) ? 1.f : 0.f;
    my[j] = (64 + i0 + j == col) ? 1.f : 0.f;
  }
  {
    const float4* src = (const float4*)(Feat + (size_t)t0 * FS);
    for (int v = tid; v < FS; v += 512) ((float4*)fb[0])[v] = src[v];
  }
  __syncthreads();
  for (int g = 0; g < LCH / 4; ++g) {
    const int cur = g & 1;
    float4 pf0, pf1;
    const bool has2 = tid < (FS - 512);
    if (g < LCH / 4 - 1) {
      const float4* src = (const float4*)(Feat + (size_t)(t0 + (g + 1) * 4) * FS);
      pf0 = src[tid];
      if (has2) pf1 = src[tid + 512];
    }
#pragma unroll
    for (int s = 0; s < 4; ++s) {
      const float* f = fb[cur] + s * FS;
      float sj[16], cj[16], k1z[16], k1y[16], k2z[16], k2y[16];
#pragma unroll
      for (int v = 0; v < 4; ++v) {
        *(float4*)&sj[4 * v]  = *(const float4*)(f + i0 + 4 * v);
        *(float4*)&cj[4 * v]  = *(const float4*)(f + 448 + i0 + 4 * v);
        *(float4*)&k1z[4 * v] = *(const float4*)(f + 64 + i0 + 4 * v);
        *(float4*)&k1y[4 * v] = *(const float4*)(f + 128 + i0 + 4 * v);
        *(float4*)&k2z[4 * v] = *(const float4*)(f + 192 + i0 + 4 * v);
        *(float4*)&k2y[4 * v] = *(const float4*)(f + 256 + i0 + 4 * v);
      }
      float4 sc = *(const float4*)(f + 512);   // b1, b2, c12, pad
      float p = 0.f, r2 = 0.f;
#pragma unroll
      for (int j = 0; j < 16; ++j) {
        float s0 = sj[j], c1 = cj[j];
        float z = mz[j], y = my[j];
        float sz = s0 * z;
        z = fmaf(-c1, y, sz);
        y = fmaf(s0, y, 0.1f * sz);
        mz[j] = z; my[j] = y;
        p  = fmaf(k1z[j], z, p);  p  = fmaf(k1y[j], y, p);
        r2 = fmaf(k2z[j], z, r2); r2 = fmaf(k2y[j], y, r2);
      }
      p  += __shfl_xor(p, 1, 64);  p  += __shfl_xor(p, 2, 64);
      r2 += __shfl_xor(r2, 1, 64); r2 += __shfl_xor(r2, 2, 64);
      float e1 = sc.x * p;
      float e2 = sc.y * fmaf(-sc.z, e1, r2);
#pragma unroll
      for (int j = 0; j < 16; ++j) {
        float z = fmaf(-e1, k1z[j], mz[j]);
        mz[j] = fmaf(-e2, k2z[j], z);
        float y = fmaf(-e1, k1y[j], my[j]);
        my[j] = fmaf(-e2, k2y[j], y);
      }
    }
    if (g < LCH / 4 - 1) {
      ((float4*)fb[1 - cur])[tid] = pf0;
      if (has2) ((float4*)fb[1 - cur])[tid + 512] = pf1;
    }
    __syncthreads();
  }
  float* dst = Mc + ((size_t)cid * 128 + col) * 128;
#pragma unroll
  for (int v = 0; v < 4; ++v)
    *(float4*)(dst + i0 + 4 * v) = *(float4*)&mz[4 * v];
#pragma unroll
  for (int v = 0; v < 4; ++v)
    *(float4*)(dst + 64 + i0 + 4 * v) = *(float4*)&my[4 * v];
}

// offset column d_c: affine replay from h=0, one wave per chunk
__global__ __launch_bounds__(64) void scanB0(
    const float* __restrict__ Feat, float* __restrict__ dc) {
  const int cid = blockIdx.x;
  const int lane = threadIdx.x;
  float z = 0.f, y = 0.f;
  const int t0 = (cid >> 6) * TT + (cid & 63) * LCH;
  for (int t = t0; t < t0 + LCH; ++t) {
    const float* __restrict__ f = Feat + (size_t)t * FS;
    float s = f[lane], c1 = f[448 + lane];
    float k1z = f[64 + lane], k1y = f[128 + lane];
    float k2z = f[192 + lane], k2y = f[256 + lane];
    float bz = f[320 + lane], by = f[384 + lane];
    float b1 = f[512], b2 = f[513], c12 = f[514];
    float sz = s * z;
    float zn = fmaf(-c1, y, sz);
    float yn = fmaf(s, y, 0.1f * sz);
    float p = fmaf(k1y, yn, k1z * zn);
    float qq = fmaf(k2y, yn, k2z * zn);
#pragma unroll
    for (int off = 32; off > 0; off >>= 1) {
      p += __shfl_xor(p, off, 64);
      qq += __shfl_xor(qq, off, 64);
    }
    float e1 = b1 * p;
    float d2 = fmaf(-c12, e1, qq);
    float e2 = b2 * d2;
    z = fmaf(-e1, k1z, zn); z = fmaf(-e2, k2z, z); z += bz;
    y = fmaf(-e1, k1y, yn); y = fmaf(-e2, k2y, y); y += by;
  }
  dc[(size_t)cid * 128 + lane] = z;
  dc[(size_t)cid * 128 + 64 + lane] = y;
}

// sequential chunk combine: h <- M_c h + d_c, store h at chunk starts.
// 1024 threads: i = tid&127, jh = tid>>7. Register double-buffer prefetch
// (ma/mb + d0/d1) under bounds(1024,1) (no VGPR cap -> no spill, cf. R4);
// raw lgkm-only barriers keep the prefetch in flight across the iteration.
__global__ __launch_bounds__(1024, 1) void scanB2(
    const float* __restrict__ Mc, const float* __restrict__ dc,
    float* __restrict__ hstart) {
  const int b = blockIdx.x;
  const int tid = threadIdx.x;
  const int i = tid & 127, jh = tid >> 7;   // jh 0..7
  __shared__ float h[128];
  __shared__ float red[8][128];
  if (tid < 128) h[tid] = 0.f;
  __syncthreads();
  float ma[16], mb[16];
  float d0, d1;
  {
    const float* M0 = Mc + (size_t)(b * CH) * 16384;
#pragma unroll
    for (int j = 0; j < 16; ++j) ma[j] = M0[(size_t)(jh * 16 + j) * 128 + i];
    d0 = dc[(size_t)(b * CH) * 128 + i];
  }
  for (int c = 0; c < CH; ++c) {
    // prefetch next chunk's M and d; waitcnt lands at the ma=mb copy after
    // the 2nd barrier -> a full iteration of latency cover, never drained.
    const int cn = (c + 1 < CH) ? c + 1 : c;
    const float* Mn = Mc + (size_t)(b * CH + cn) * 16384;
#pragma unroll
    for (int j = 0; j < 16; ++j) mb[j] = Mn[(size_t)(jh * 16 + j) * 128 + i];
    d1 = dc[(size_t)(b * CH + cn) * 128 + i];
    if (tid < 128) hstart[(size_t)(b * CH + c) * 128 + tid] = h[tid];
    float acc = 0.f;
#pragma unroll
    for (int j = 0; j < 16; ++j) acc = fmaf(ma[j], h[jh * 16 + j], acc);
    red[jh][i] = acc;
    RAW_BAR();
    if (tid < 128) {
      float sum = d0;
#pragma unroll
      for (int k = 0; k < 8; ++k) sum += red[k][tid];
      h[tid] = sum;
    }
    RAW_BAR();
#pragma unroll
    for (int j = 0; j < 16; ++j) ma[j] = mb[j];
    d0 = d1;
  }
}

// replay within chunk from h_start, one wave per chunk; write split bf16 hs
// in the tiled swizzled layout for gemmC_mfma.
__global__ __launch_bounds__(64) void scanB3(
    const float* __restrict__ Feat, const float* __restrict__ hstart,
    unsigned short* __restrict__ hsh, unsigned short* __restrict__ hsl) {
  const int cid = blockIdx.x;
  const int lane = threadIdx.x;
  float z = hstart[(size_t)cid * 128 + lane];
  float y = hstart[(size_t)cid * 128 + 64 + lane];
  const int t0 = (cid >> 6) * TT + (cid & 63) * LCH;
  const int ktz = lane >> 5, kkz = lane & 31;
  const int kty = (64 + lane) >> 5;
  const int pz = (kkz >> 2) & 3, hz = kkz >> 4;
  const int lowz = kkz & 3;
  for (int t = t0; t < t0 + LCH; ++t) {
    const float* __restrict__ f = Feat + (size_t)t * FS;
    float s = f[lane], c1 = f[448 + lane];
    float k1z = f[64 + lane], k1y = f[128 + lane];
    float k2z = f[192 + lane], k2y = f[256 + lane];
    float bz = f[320 + lane], by = f[384 + lane];
    float b1 = f[512], b2 = f[513], c12 = f[514];
    float sz = s * z;
    float zn = fmaf(-c1, y, sz);
    float yn = fmaf(s, y, 0.1f * sz);
    float p = fmaf(k1y, yn, k1z * zn);
    float qq = fmaf(k2y, yn, k2z * zn);
#pragma unroll
    for (int off = 32; off > 0; off >>= 1) {
      p += __shfl_xor(p, off, 64);
      qq += __shfl_xor(qq, off, 64);
    }
    float e1 = b1 * p;
    float d2 = fmaf(-c12, e1, qq);
    float e2 = b2 * d2;
    zn = fmaf(-e1, k1z, zn); zn = fmaf(-e2, k2z, zn); zn += bz;
    yn = fmaf(-e1, k1y, yn); yn = fmaf(-e2, k2y, yn); yn += by;
    {
      const int mb = t >> 7, mr = t & 127;
      const int xr = (mr >> 2) & 3;
      size_t idxz = ((size_t)(mb * 4 + ktz)) * 4096 + mr * 32 +
                    ((((pz ^ xr) << 1) | hz)) * 4 + lowz;
      size_t idxy = ((size_t)(mb * 4 + kty)) * 4096 + mr * 32 +
                    ((((pz ^ xr) << 1) | hz)) * 4 + lowz;
      unsigned short hi, lo;
      split_bf16(zn, hi, lo);
      hsh[idxz] = hi; hsl[idxz] = lo;
      split_bf16(yn, hi, lo);
      hsh[idxy] = hi; hsl[idxy] = lo;
    }
    z = zn; y = yn;
  }
}

extern "C" void kernel_launch(void* const* d_in, const int* in_sizes, int n_in,
                              void* d_out, int out_size, void* d_ws, size_t ws_size,
                              hipStream_t stream) {
  const float* u      = (const float*)d_in[0];
  const float* W_A    = (const float*)d_in[1];
  const float* b_A    = (const float*)d_in[2];
  const float* W_k    = (const float*)d_in[3];
  const float* b_k    = (const float*)d_in[4];
  const float* W_beta = (const float*)d_in[5];
  const float* b_beta = (const float*)d_in[6];
  const float* B_w    = (const float*)d_in[7];
  const float* B_b    = (const float*)d_in[8];
  const float* Cm     = (const float*)d_in[9];
  const float* Dv     = (const float*)d_in[10];
  float* out = (float*)d_out;
  char* ws = (char*)d_ws;
  // workspace carve-up (~105.4 MB):
  //  (Wp slot retired; offsets unchanged)
  //  Wb    1,835,008  1,048,576
  //  bias  4,194,304  4,096
  //  Feat  4,198,400  34,078,720           -> ends 38,277,120
  //  uh    38,277,120 33,554,432  [dead after gemmA]
  //  Mc    38,277,120 33,554,432  (512*128*128*4, overlays uh)
  //  ul    71,831,552 33,554,432  [dead after gemmA pass 2]
  //   hsh  71,831,552 4,194,304   (overlays ul)
  //   hsl  76,025,856 4,194,304
  //   Chp  80,220,160 262,144
  //   Clp  80,482,304 262,144
  //   dcv  80,744,448 262,144
  //   hst  81,006,592 262,144     -> ends 81,268,736 (< ul end)
  unsigned short* Wb = (unsigned short*)(ws + 1835008);
  float* bias   = (float*)(ws + 4194304);
  float* Feat   = (float*)(ws + 4198400);
  unsigned short* uh = (unsigned short*)(ws + 38277120);
  float* Mc     = (float*)(ws + 38277120);
  unsigned short* ul = (unsigned short*)(ws + 71831552);
  unsigned short* hsh = (unsigned short*)(ws + 71831552);
  unsigned short* hsl = (unsigned short*)(ws + 76025856);
  unsigned short* Chp = (unsigned short*)(ws + 80220160);
  unsigned short* Clp = (unsigned short*)(ws + 80482304);
  float* dcv    = (float*)(ws + 80744448);
  float* hstart = (float*)(ws + 81006592);

  convertW<<<dim3(512), dim3(256), 0, stream>>>(W_A, W_k, B_w, b_A, b_k,
                                                B_b, b_beta, Wb, bias);
  convertU<<<dim3(16384), dim3(256), 0, stream>>>(u, uh, ul);
  gemmA_mfma<<<dim3(128, 4), dim3(256), 0, stream>>>(uh, ul, Wb, Feat);
  convertC<<<dim3(128), dim3(256), 0, stream>>>(Cm, Chp, Clp);
  postA<<<dim3(16384), dim3(64), 0, stream>>>(Feat, bias, u, W_beta);
  scanB1<<<dim3(NCH), dim3(512), 0, stream>>>(Feat, Mc);
  scanB0<<<dim3(NCH), dim3(64), 0, stream>>>(Feat, dcv);
  scanB2<<<dim3(8), dim3(1024), 0, stream>>>(Mc, dcv, hstart);
  scanB3<<<dim3(NCH), dim3(64), 0, stream>>>(Feat, hstart, hsh, hsl);
  gemmC_mfma<<<dim3(128, 8), dim3(256), 0, stream>>>(hsh, hsl, Chp, Clp,
                                                     u, Dv, out);
}

// Round 9
// 396.880 us; speedup vs baseline: 1.2599x; 1.0118x over previous
//
#include <hip/hip_runtime.h>
#include <cmath>

// ---------------------------------------------------------------------------
// OHDeltaProductSSM: u(8,2048,1024) -> out(8,2048,1024), fp32.
// Round 9: gemmA deep pipeline. R8 profile: gemmA 67us, MfmaUtil 20%,
// occupancy grid-capped at 2 blocks/CU -> the 1-deep 2-phase stalls
// ~200-400cy per K-step on load latency (16 MFMA = only ~80cy of cover).
// New: 4-buffer, 3-ahead pipeline with counted WAIT_VM(8) (drain only
// stage(s+1), keep 8 newest in flight) + raw lgkm-only barriers — the same
// T4 pattern validated in scanB2 (R8). Tail: uniform-branch 8/4/0 waits.
// LDS 32->64KB (still 2 blocks/CU, grid-capped anyway). gemmC frozen this
// round (runs 4-5 blocks/CU; TLP already covers its latency).
// Round 8 (kept): scanB2 reg-dbuf under bounds(1024,1); packW eliminated.
// Round 6 (kept): scanB1 round-2 shape; standalone scanB0. Round 3: LCH=32.
// Round 2: gemmC 3-pass split MFMA. Round 1: gemmA 2-pass split bf16 MFMA.
// Tiled operand layout: tile (rowblk, kt) = 128x32 bf16, 8 KB contiguous;
//   elem (r,k): g=k>>2, p=g&3, h=g>>2, s'=((p^((r>>2)&3))<<1)|h,
//   index = r*32 + s'*4 + (k&3); identical permutation on A and B.
// MFMA facts: A row = lane&15, B col = lane&15, D: col=lane&15,
// row = 4*(lane>>4)+reg  [guide m89/m91].
// ---------------------------------------------------------------------------

#define NTOK 16384
#define TT 2048
#define BB 8
#define DM 1024
#define FS 520
#define CH 64          // chunks per batch
#define LCH 32         // tokens per chunk
#define NCH 512        // total chunks
#define NW 448
#define NWP 512

typedef short bf16x8 __attribute__((ext_vector_type(8)));
typedef float f32x4 __attribute__((ext_vector_type(4)));

#define GLOAD_LDS16(g, l)                                          \
  __builtin_amdgcn_global_load_lds(                                \
      (const __attribute__((address_space(1))) void*)(g),          \
      (__attribute__((address_space(3))) void*)(l), 16, 0, 0)

// raw workgroup barrier that does NOT drain vmcnt (keeps global prefetches
// in flight). LDS ordering via lgkmcnt(0); sched_barrier fences both sides.
#define RAW_BAR() do {                                             \
    asm volatile("s_waitcnt lgkmcnt(0)" ::: "memory");             \
    __builtin_amdgcn_sched_barrier(0);                             \
    __builtin_amdgcn_s_barrier();                                  \
    __builtin_amdgcn_sched_barrier(0);                             \
  } while (0)

#define WAIT_VM(N) do {                                            \
    __builtin_amdgcn_sched_barrier(0);                             \
    asm volatile("s_waitcnt vmcnt(" #N ")" ::: "memory");          \
    __builtin_amdgcn_sched_barrier(0);                             \
  } while (0)

__device__ inline unsigned short bf16_rne(float x) {
  unsigned b = __float_as_uint(x);
  b += 0x7FFFu + ((b >> 16) & 1u);
  return (unsigned short)(b >> 16);
}

__device__ inline void split_bf16(float x, unsigned short& h, unsigned short& l) {
  unsigned b = __float_as_uint(x);
  h = (unsigned short)(b >> 16);                       // truncated high part
  float rem = x - __uint_as_float(b & 0xFFFF0000u);    // exact remainder
  l = bf16_rne(rem);
}

// u fp32 -> u_hi/u_lo bf16, tiled (mb,kt) 128x32, swizzled granules.
__global__ __launch_bounds__(256) void convertU(
    const float* __restrict__ u, unsigned short* __restrict__ uh,
    unsigned short* __restrict__ ul) {
  int gid = blockIdx.x * 256 + threadIdx.x;
  int m = gid >> 8;          // token row
  int g = gid & 255;         // granule along k
  float4 v = *(const float4*)(u + (size_t)m * DM + g * 4);
  int kt = g >> 3, gg = g & 7;
  int p = gg & 3, h = gg >> 2;
  int mr = m & 127, mb = m >> 7;
  int pp = p ^ ((mr >> 2) & 3);
  size_t dst = ((size_t)(mb * 32 + kt)) * 4096 + mr * 32 + ((pp << 1) | h) * 4;
  ushort4 hi, lo;
  split_bf16(v.x, hi.x, lo.x);
  split_bf16(v.y, hi.y, lo.y);
  split_bf16(v.z, hi.z, lo.z);
  split_bf16(v.w, hi.w, lo.w);
  *(ushort4*)(uh + dst) = hi;
  *(ushort4*)(ul + dst) = lo;
}

// weights -> Wb bf16 tiled (nb,kt) 128x32, rows 448..511 zero. Reads the
// original W_A/W_k/B_w directly (packW eliminated). Block 448 writes bias.
__global__ __launch_bounds__(256) void convertW(
    const float* __restrict__ W_A, const float* __restrict__ W_k,
    const float* __restrict__ B_w, const float* __restrict__ b_A,
    const float* __restrict__ b_k, const float* __restrict__ B_b,
    const float* __restrict__ b_beta, unsigned short* __restrict__ Wb,
    float* __restrict__ bias) {
  int n = blockIdx.x;        // 0..511 (row)
  int g = threadIdx.x;       // granule along k
  int kt = g >> 3, gg = g & 7;
  int p = gg & 3, h = gg >> 2;
  int nr = n & 127, nb = n >> 7;
  int pp = p ^ ((nr >> 2) & 3);
  size_t dst = ((size_t)(nb * 32 + kt)) * 4096 + nr * 32 + ((pp << 1) | h) * 4;
  ushort4 hv = make_ushort4(0, 0, 0, 0);
  if (n < NW) {
    const float* src;
    if (n < 64)       src = W_A + (size_t)n * DM;
    else if (n < 320) src = W_k + (size_t)(n - 64) * DM;
    else              src = B_w + (size_t)(n - 320) * DM;
    float4 v = *(const float4*)(src + g * 4);
    hv.x = bf16_rne(v.x); hv.y = bf16_rne(v.y);
    hv.z = bf16_rne(v.z); hv.w = bf16_rne(v.w);
  }
  *(ushort4*)(Wb + dst) = hv;
  if (n == 448) {
    for (int i = threadIdx.x; i < 450; i += 256) {
      float bv;
      if (i < 64)       bv = b_A[i];
      else if (i < 320) bv = b_k[i - 64];
      else if (i < 448) bv = B_b[i - 320];
      else              bv = b_beta[i - 448];
      bias[i] = bv;
    }
  }
}

// Cm[1024][128] fp32 -> C_hi/C_lo bf16 tiled (nb,kt).
__global__ __launch_bounds__(256) void convertC(
    const float* __restrict__ Cm, unsigned short* __restrict__ Chp,
    unsigned short* __restrict__ Clp) {
  int gid = blockIdx.x * 256 + threadIdx.x;   // 32768 total
  int d = gid >> 5;          // 0..1023
  int g = gid & 31;          // granule along 128
  float4 v = *(const float4*)(Cm + (size_t)d * 128 + g * 4);
  int kt = g >> 3, gg = g & 7;
  int p = gg & 3, h = gg >> 2;
  int nr = d & 127, nb = d >> 7;
  int pp = p ^ ((nr >> 2) & 3);
  size_t dst = ((size_t)(nb * 4 + kt)) * 4096 + nr * 32 + ((pp << 1) | h) * 4;
  ushort4 hi, lo;
  split_bf16(v.x, hi.x, lo.x);
  split_bf16(v.y, hi.y, lo.y);
  split_bf16(v.z, hi.z, lo.z);
  split_bf16(v.w, hi.w, lo.w);
  *(ushort4*)(Chp + dst) = hi;
  *(ushort4*)(Clp + dst) = lo;
}

// Feat[0..512) = (u_hi + u_lo) . Wb^T via MFMA. 128x128 tile, BK=32.
// 4-buffer, 3-ahead pipeline: counted WAIT_VM(8) keeps 2 stages in flight
// across raw lgkm-only barriers (T4; validated in scanB2).
__global__ __launch_bounds__(256) void gemmA_mfma(
    const unsigned short* __restrict__ uh, const unsigned short* __restrict__ ul,
    const unsigned short* __restrict__ Wb, float* __restrict__ Feat) {
  __shared__ __align__(16) unsigned short As[4][4096];
  __shared__ __align__(16) unsigned short Bs[4][4096];
  const int tid = threadIdx.x;
  const int wv = tid >> 6, ln = tid & 63;
  const int lr = ln & 15, G = ln >> 4;
  const int wm = wv >> 1, wn = wv & 1;
  const int x = G ^ (lr >> 2);
  f32x4 acc[4][4];
#pragma unroll
  for (int i = 0; i < 4; ++i)
#pragma unroll
    for (int j = 0; j < 4; ++j) acc[i][j] = (f32x4){0.f, 0.f, 0.f, 0.f};

  const size_t aBase = (size_t)blockIdx.x * 32 * 4096;
  const size_t bBase = (size_t)blockIdx.y * 32 * 4096;
  const int so = wv * 512 + ln * 8;
  const int ld = wv * 512;

  auto stage = [&](int step) {
    const unsigned short* pa = (step < 32) ? uh : ul;
    const int kt = step & 31;
    const unsigned short* ga = pa + aBase + (size_t)kt * 4096;
    const unsigned short* gb = Wb + bBase + (size_t)kt * 4096;
    unsigned short* A = As[step & 3];
    unsigned short* B = Bs[step & 3];
    GLOAD_LDS16(ga + so,        A + ld);
    GLOAD_LDS16(ga + 2048 + so, A + 2048 + ld);
    GLOAD_LDS16(gb + so,        B + ld);
    GLOAD_LDS16(gb + 2048 + so, B + 2048 + ld);
  };

  stage(0); stage(1); stage(2);   // 12 vm outstanding
  WAIT_VM(8);                     // own stage(0) landed
  RAW_BAR();                      // all waves' stage(0) landed
  for (int s = 0; s < 64; ++s) {
    if (s + 3 < 64) stage(s + 3); // outstanding -> 12 (stages s+1,s+2,s+3)
    bf16x8 af[4], bfr[4];
    const char* Ab = (const char*)As[s & 3] + ((wm * 64 + lr) << 6) + (x << 4);
    const char* Bb = (const char*)Bs[s & 3] + ((wn * 64 + lr) << 6) + (x << 4);
#pragma unroll
    for (int i = 0; i < 4; ++i) {
      af[i]  = *(const bf16x8*)(Ab + i * 1024);
      bfr[i] = *(const bf16x8*)(Bb + i * 1024);
    }
#pragma unroll
    for (int i = 0; i < 4; ++i)
#pragma unroll
      for (int j = 0; j < 4; ++j)
        acc[i][j] = __builtin_amdgcn_mfma_f32_16x16x32_bf16(
            af[i], bfr[j], acc[i][j], 0, 0, 0);
    // drain stage(s+1) (read next iter); keep newer stages in flight
    if (s < 61)       WAIT_VM(8);
    else if (s == 61) WAIT_VM(4);
    else if (s == 62) WAIT_VM(0);
    RAW_BAR();
  }
  const int row0 = (blockIdx.x << 7) + wm * 64 + (G << 2);
  const int col0 = (blockIdx.y << 7) + wn * 64 + lr;
  float* fb = Feat + (size_t)row0 * FS + col0;
#pragma unroll
  for (int i = 0; i < 4; ++i)
#pragma unroll
    for (int j = 0; j < 4; ++j) {
      float* d = fb + (size_t)(i * 16) * FS + j * 16;
#pragma unroll
      for (int r = 0; r < 4; ++r) d[(size_t)r * FS] = acc[i][j][r];
    }
}

// out = hs.C^T + u*D via MFMA, 3 passes (hh, lh, hl), 2-phase dbuf.
__global__ __launch_bounds__(256) void gemmC_mfma(
    const unsigned short* __restrict__ hsh, const unsigned short* __restrict__ hsl,
    const unsigned short* __restrict__ Chp, const unsigned short* __restrict__ Clp,
    const float* __restrict__ u, const float* __restrict__ Dv,
    float* __restrict__ out) {
  __shared__ __align__(16) unsigned short As[8192];
  __shared__ __align__(16) unsigned short Bs[8192];
  const int tid = threadIdx.x;
  const int wv = tid >> 6, ln = tid & 63;
  const int lr = ln & 15, G = ln >> 4;
  const int wm = wv >> 1, wn = wv & 1;
  const int x = G ^ (lr >> 2);
  f32x4 acc[4][4];
#pragma unroll
  for (int i = 0; i < 4; ++i)
#pragma unroll
    for (int j = 0; j < 4; ++j) acc[i][j] = (f32x4){0.f, 0.f, 0.f, 0.f};

  const size_t aBase = (size_t)blockIdx.x * 4 * 4096;
  const size_t bBase = (size_t)blockIdx.y * 4 * 4096;
  const int so = wv * 512 + ln * 8;
  const int ld = wv * 512;

  auto stage = [&](int step, int buf) {
    const int pass = step >> 2, kt = step & 3;
    const unsigned short* pa = (pass == 1) ? hsl : hsh;
    const unsigned short* pb = (pass == 2) ? Clp : Chp;
    const unsigned short* ga = pa + aBase + (size_t)kt * 4096;
    const unsigned short* gb = pb + bBase + (size_t)kt * 4096;
    unsigned short* A = As + buf * 4096;
    unsigned short* B = Bs + buf * 4096;
    GLOAD_LDS16(ga + so,        A + ld);
    GLOAD_LDS16(ga + 2048 + so, A + 2048 + ld);
    GLOAD_LDS16(gb + so,        B + ld);
    GLOAD_LDS16(gb + 2048 + so, B + 2048 + ld);
  };

  stage(0, 0);
  __syncthreads();
  for (int s = 0; s < 12; ++s) {
    const int cur = s & 1;
    if (s + 1 < 12) stage(s + 1, cur ^ 1);
    bf16x8 af[4], bfr[4];
    const char* Ab = (const char*)(As + cur * 4096) + ((wm * 64 + lr) << 6) + (x << 4);
    const char* Bb = (const char*)(Bs + cur * 4096) + ((wn * 64 + lr) << 6) + (x << 4);
#pragma unroll
    for (int i = 0; i < 4; ++i) {
      af[i]  = *(const bf16x8*)(Ab + i * 1024);
      bfr[i] = *(const bf16x8*)(Bb + i * 1024);
    }
#pragma unroll
    for (int i = 0; i < 4; ++i)
#pragma unroll
      for (int j = 0; j < 4; ++j)
        acc[i][j] = __builtin_amdgcn_mfma_f32_16x16x32_bf16(
            af[i], bfr[j], acc[i][j], 0, 0, 0);
    __syncthreads();
  }
  const int row0 = (blockIdx.x << 7) + wm * 64 + (G << 2);
  const int col0 = (blockIdx.y << 7) + wn * 64 + lr;
#pragma unroll
  for (int j = 0; j < 4; ++j) {
    float dv = Dv[col0 + j * 16];
#pragma unroll
    for (int i = 0; i < 4; ++i) {
#pragma unroll
      for (int r = 0; r < 4; ++r) {
        size_t off = (size_t)(row0 + i * 16 + r) * DM + col0 + j * 16;
        out[off] = fmaf(u[off], dv, acc[i][j][r]);
      }
    }
  }
}

__device__ inline float wave_sum(float v) {
#pragma unroll
  for (int off = 32; off > 0; off >>= 1) v += __shfl_xor(v, off, 64);
  return v;
}

// per-token nonlinearity, one wave per token, in-place in Feat
__global__ __launch_bounds__(64) void postA(float* __restrict__ Feat,
                                            const float* __restrict__ bias,
                                            const float* __restrict__ u,
                                            const float* __restrict__ Wb) {
  const int t = blockIdx.x, lane = threadIdx.x;
  float* f = Feat + (size_t)t * FS;
  float s0 = 0.f, s1 = 0.f;
#pragma unroll
  for (int j = 0; j < 4; ++j) {
    float4 uv = *(const float4*)(u + (size_t)t * DM + j * 256 + lane * 4);
    float4 w0 = *(const float4*)(Wb + j * 256 + lane * 4);
    float4 w1 = *(const float4*)(Wb + DM + j * 256 + lane * 4);
    s0 = fmaf(uv.x, w0.x, s0); s0 = fmaf(uv.y, w0.y, s0);
    s0 = fmaf(uv.z, w0.z, s0); s0 = fmaf(uv.w, w0.w, s0);
    s1 = fmaf(uv.x, w1.x, s1); s1 = fmaf(uv.y, w1.y, s1);
    s1 = fmaf(uv.z, w1.z, s1); s1 = fmaf(uv.w, w1.w, s1);
  }
  s0 = wave_sum(s0); s1 = wave_sum(s1);
  float a = f[lane] + bias[lane];
  a = fminf(fmaxf(a, 0.f), 100.f);
  float S = 1.f / (1.f + 0.01f * a);
  f[lane] = S;
  f[448 + lane] = 0.1f * a * S;
  float k10 = f[64 + lane] + bias[64 + lane];
  float k11 = f[128 + lane] + bias[128 + lane];
  float n1 = wave_sum(k10 * k10 + k11 * k11);
  float inv1 = 1.f / fmaxf(sqrtf(n1), 1e-12f);
  k10 *= inv1; k11 *= inv1;
  f[64 + lane] = k10; f[128 + lane] = k11;
  float k20 = f[192 + lane] + bias[192 + lane];
  float k21 = f[256 + lane] + bias[256 + lane];
  float n2 = wave_sum(k20 * k20 + k21 * k21);
  float inv2 = 1.f / fmaxf(sqrtf(n2), 1e-12f);
  k20 *= inv2; k21 *= inv2;
  f[192 + lane] = k20; f[256 + lane] = k21;
  float c12 = wave_sum(k10 * k20 + k11 * k21);
  if (lane == 0) {
    f[512] = 2.f / (1.f + expf(-(s0 + bias[448])));
    f[513] = 2.f / (1.f + expf(-(s1 + bias[449])));
    f[514] = c12;
  }
  f[320 + lane] += bias[320 + lane];
  f[384 + lane] += bias[384 + lane];
}

// chunk transition matrices. Round-2-verified shape: 512 threads,
// col = tid>>2 (0..127), quarter q = tid&3, 16 elems/thread, VGPR=64.
__global__ __launch_bounds__(512, 2) void scanB1(
    const float* __restrict__ Feat, float* __restrict__ Mc) {
  const int cid = blockIdx.x;              // 0..511 = b*64 + chunk
  const int t0 = (cid >> 6) * TT + (cid & 63) * LCH;
  const int tid = threadIdx.x;
  const int col = tid >> 2, q = tid & 3;
  const int i0 = q * 16;
  __shared__ float fb[2][4 * FS];
  float mz[16], my[16];
#pragma unroll
  for (int j = 0; j < 16; ++j) {
    mz[j] = (i0 + j == col) ? 1.f : 0.f;
    my[j] = (64 + i0 + j == col) ? 1.f : 0.f;
  }
  {
    const float4* src = (const float4*)(Feat + (size_t)t0 * FS);
    for (int v = tid; v < FS; v += 512) ((float4*)fb[0])[v] = src[v];
  }
  __syncthreads();
  for (int g = 0; g < LCH / 4; ++g) {
    const int cur = g & 1;
    float4 pf0, pf1;
    const bool has2 = tid < (FS - 512);
    if (g < LCH / 4 - 1) {
      const float4* src = (const float4*)(Feat + (size_t)(t0 + (g + 1) * 4) * FS);
      pf0 = src[tid];
      if (has2) pf1 = src[tid + 512];
    }
#pragma unroll
    for (int s = 0; s < 4; ++s) {
      const float* f = fb[cur] + s * FS;
      float sj[16], cj[16], k1z[16], k1y[16], k2z[16], k2y[16];
#pragma unroll
      for (int v = 0; v < 4; ++v) {
        *(float4*)&sj[4 * v]  = *(const float4*)(f + i0 + 4 * v);
        *(float4*)&cj[4 * v]  = *(const float4*)(f + 448 + i0 + 4 * v);
        *(float4*)&k1z[4 * v] = *(const float4*)(f + 64 + i0 + 4 * v);
        *(float4*)&k1y[4 * v] = *(const float4*)(f + 128 + i0 + 4 * v);
        *(float4*)&k2z[4 * v] = *(const float4*)(f + 192 + i0 + 4 * v);
        *(float4*)&k2y[4 * v] = *(const float4*)(f + 256 + i0 + 4 * v);
      }
      float4 sc = *(const float4*)(f + 512);   // b1, b2, c12, pad
      float p = 0.f, r2 = 0.f;
#pragma unroll
      for (int j = 0; j < 16; ++j) {
        float s0 = sj[j], c1 = cj[j];
        float z = mz[j], y = my[j];
        float sz = s0 * z;
        z = fmaf(-c1, y, sz);
        y = fmaf(s0, y, 0.1f * sz);
        mz[j] = z; my[j] = y;
        p  = fmaf(k1z[j], z, p);  p  = fmaf(k1y[j], y, p);
        r2 = fmaf(k2z[j], z, r2); r2 = fmaf(k2y[j], y, r2);
      }
      p  += __shfl_xor(p, 1, 64);  p  += __shfl_xor(p, 2, 64);
      r2 += __shfl_xor(r2, 1, 64); r2 += __shfl_xor(r2, 2, 64);
      float e1 = sc.x * p;
      float e2 = sc.y * fmaf(-sc.z, e1, r2);
#pragma unroll
      for (int j = 0; j < 16; ++j) {
        float z = fmaf(-e1, k1z[j], mz[j]);
        mz[j] = fmaf(-e2, k2z[j], z);
        float y = fmaf(-e1, k1y[j], my[j]);
        my[j] = fmaf(-e2, k2y[j], y);
      }
    }
    if (g < LCH / 4 - 1) {
      ((float4*)fb[1 - cur])[tid] = pf0;
      if (has2) ((float4*)fb[1 - cur])[tid + 512] = pf1;
    }
    __syncthreads();
  }
  float* dst = Mc + ((size_t)cid * 128 + col) * 128;
#pragma unroll
  for (int v = 0; v < 4; ++v)
    *(float4*)(dst + i0 + 4 * v) = *(float4*)&mz[4 * v];
#pragma unroll
  for (int v = 0; v < 4; ++v)
    *(float4*)(dst + 64 + i0 + 4 * v) = *(float4*)&my[4 * v];
}

// offset column d_c: affine replay from h=0, one wave per chunk
__global__ __launch_bounds__(64) void scanB0(
    const float* __restrict__ Feat, float* __restrict__ dc) {
  const int cid = blockIdx.x;
  const int lane = threadIdx.x;
  float z = 0.f, y = 0.f;
  const int t0 = (cid >> 6) * TT + (cid & 63) * LCH;
  for (int t = t0; t < t0 + LCH; ++t) {
    const float* __restrict__ f = Feat + (size_t)t * FS;
    float s = f[lane], c1 = f[448 + lane];
    float k1z = f[64 + lane], k1y = f[128 + lane];
    float k2z = f[192 + lane], k2y = f[256 + lane];
    float bz = f[320 + lane], by = f[384 + lane];
    float b1 = f[512], b2 = f[513], c12 = f[514];
    float sz = s * z;
    float zn = fmaf(-c1, y, sz);
    float yn = fmaf(s, y, 0.1f * sz);
    float p = fmaf(k1y, yn, k1z * zn);
    float qq = fmaf(k2y, yn, k2z * zn);
#pragma unroll
    for (int off = 32; off > 0; off >>= 1) {
      p += __shfl_xor(p, off, 64);
      qq += __shfl_xor(qq, off, 64);
    }
    float e1 = b1 * p;
    float d2 = fmaf(-c12, e1, qq);
    float e2 = b2 * d2;
    z = fmaf(-e1, k1z, zn); z = fmaf(-e2, k2z, z); z += bz;
    y = fmaf(-e1, k1y, yn); y = fmaf(-e2, k2y, y); y += by;
  }
  dc[(size_t)cid * 128 + lane] = z;
  dc[(size_t)cid * 128 + 64 + lane] = y;
}

// sequential chunk combine: h <- M_c h + d_c, store h at chunk starts.
// 1024 threads: i = tid&127, jh = tid>>7. Register double-buffer prefetch
// (ma/mb + d0/d1) under bounds(1024,1) (no VGPR cap -> no spill, cf. R4);
// raw lgkm-only barriers keep the prefetch in flight across the iteration.
__global__ __launch_bounds__(1024, 1) void scanB2(
    const float* __restrict__ Mc, const float* __restrict__ dc,
    float* __restrict__ hstart) {
  const int b = blockIdx.x;
  const int tid = threadIdx.x;
  const int i = tid & 127, jh = tid >> 7;   // jh 0..7
  __shared__ float h[128];
  __shared__ float red[8][128];
  if (tid < 128) h[tid] = 0.f;
  __syncthreads();
  float ma[16], mb[16];
  float d0, d1;
  {
    const float* M0 = Mc + (size_t)(b * CH) * 16384;
#pragma unroll
    for (int j = 0; j < 16; ++j) ma[j] = M0[(size_t)(jh * 16 + j) * 128 + i];
    d0 = dc[(size_t)(b * CH) * 128 + i];
  }
  for (int c = 0; c < CH; ++c) {
    // prefetch next chunk's M and d; waitcnt lands at the ma=mb copy after
    // the 2nd barrier -> a full iteration of latency cover, never drained.
    const int cn = (c + 1 < CH) ? c + 1 : c;
    const float* Mn = Mc + (size_t)(b * CH + cn) * 16384;
#pragma unroll
    for (int j = 0; j < 16; ++j) mb[j] = Mn[(size_t)(jh * 16 + j) * 128 + i];
    d1 = dc[(size_t)(b * CH + cn) * 128 + i];
    if (tid < 128) hstart[(size_t)(b * CH + c) * 128 + tid] = h[tid];
    float acc = 0.f;
#pragma unroll
    for (int j = 0; j < 16; ++j) acc = fmaf(ma[j], h[jh * 16 + j], acc);
    red[jh][i] = acc;
    RAW_BAR();
    if (tid < 128) {
      float sum = d0;
#pragma unroll
      for (int k = 0; k < 8; ++k) sum += red[k][tid];
      h[tid] = sum;
    }
    RAW_BAR();
#pragma unroll
    for (int j = 0; j < 16; ++j) ma[j] = mb[j];
    d0 = d1;
  }
}

// replay within chunk from h_start, one wave per chunk; write split bf16 hs
// in the tiled swizzled layout for gemmC_mfma.
__global__ __launch_bounds__(64) void scanB3(
    const float* __restrict__ Feat, const float* __restrict__ hstart,
    unsigned short* __restrict__ hsh, unsigned short* __restrict__ hsl) {
  const int cid = blockIdx.x;
  const int lane = threadIdx.x;
  float z = hstart[(size_t)cid * 128 + lane];
  float y = hstart[(size_t)cid * 128 + 64 + lane];
  const int t0 = (cid >> 6) * TT + (cid & 63) * LCH;
  const int ktz = lane >> 5, kkz = lane & 31;
  const int kty = (64 + lane) >> 5;
  const int pz = (kkz >> 2) & 3, hz = kkz >> 4;
  const int lowz = kkz & 3;
  for (int t = t0; t < t0 + LCH; ++t) {
    const float* __restrict__ f = Feat + (size_t)t * FS;
    float s = f[lane], c1 = f[448 + lane];
    float k1z = f[64 + lane], k1y = f[128 + lane];
    float k2z = f[192 + lane], k2y = f[256 + lane];
    float bz = f[320 + lane], by = f[384 + lane];
    float b1 = f[512], b2 = f[513], c12 = f[514];
    float sz = s * z;
    float zn = fmaf(-c1, y, sz);
    float yn = fmaf(s, y, 0.1f * sz);
    float p = fmaf(k1y, yn, k1z * zn);
    float qq = fmaf(k2y, yn, k2z * zn);
#pragma unroll
    for (int off = 32; off > 0; off >>= 1) {
      p += __shfl_xor(p, off, 64);
      qq += __shfl_xor(qq, off, 64);
    }
    float e1 = b1 * p;
    float d2 = fmaf(-c12, e1, qq);
    float e2 = b2 * d2;
    zn = fmaf(-e1, k1z, zn); zn = fmaf(-e2, k2z, zn); zn += bz;
    yn = fmaf(-e1, k1y, yn); yn = fmaf(-e2, k2y, yn); yn += by;
    {
      const int mb = t >> 7, mr = t & 127;
      const int xr = (mr >> 2) & 3;
      size_t idxz = ((size_t)(mb * 4 + ktz)) * 4096 + mr * 32 +
                    ((((pz ^ xr) << 1) | hz)) * 4 + lowz;
      size_t idxy = ((size_t)(mb * 4 + kty)) * 4096 + mr * 32 +
                    ((((pz ^ xr) << 1) | hz)) * 4 + lowz;
      unsigned short hi, lo;
      split_bf16(zn, hi, lo);
      hsh[idxz] = hi; hsl[idxz] = lo;
      split_bf16(yn, hi, lo);
      hsh[idxy] = hi; hsl[idxy] = lo;
    }
    z = zn; y = yn;
  }
}

extern "C" void kernel_launch(void* const* d_in, const int* in_sizes, int n_in,
                              void* d_out, int out_size, void* d_ws, size_t ws_size,
                              hipStream_t stream) {
  const float* u      = (const float*)d_in[0];
  const float* W_A    = (const float*)d_in[1];
  const float* b_A    = (const float*)d_in[2];
  const float* W_k    = (const float*)d_in[3];
  const float* b_k    = (const float*)d_in[4];
  const float* W_beta = (const float*)d_in[5];
  const float* b_beta = (const float*)d_in[6];
  const float* B_w    = (const float*)d_in[7];
  const float* B_b    = (const float*)d_in[8];
  const float* Cm     = (const float*)d_in[9];
  const float* Dv     = (const float*)d_in[10];
  float* out = (float*)d_out;
  char* ws = (char*)d_ws;
  // workspace carve-up (~105.4 MB):
  //  Wb    1,835,008  1,048,576
  //  bias  4,194,304  4,096
  //  Feat  4,198,400  34,078,720           -> ends 38,277,120
  //  uh    38,277,120 33,554,432  [dead after gemmA]
  //  Mc    38,277,120 33,554,432  (512*128*128*4, overlays uh)
  //  ul    71,831,552 33,554,432  [dead after gemmA pass 2]
  //   hsh  71,831,552 4,194,304   (overlays ul)
  //   hsl  76,025,856 4,194,304
  //   Chp  80,220,160 262,144
  //   Clp  80,482,304 262,144
  //   dcv  80,744,448 262,144
  //   hst  81,006,592 262,144     -> ends 81,268,736 (< ul end)
  unsigned short* Wb = (unsigned short*)(ws + 1835008);
  float* bias   = (float*)(ws + 4194304);
  float* Feat   = (float*)(ws + 4198400);
  unsigned short* uh = (unsigned short*)(ws + 38277120);
  float* Mc     = (float*)(ws + 38277120);
  unsigned short* ul = (unsigned short*)(ws + 71831552);
  unsigned short* hsh = (unsigned short*)(ws + 71831552);
  unsigned short* hsl = (unsigned short*)(ws + 76025856);
  unsigned short* Chp = (unsigned short*)(ws + 80220160);
  unsigned short* Clp = (unsigned short*)(ws + 80482304);
  float* dcv    = (float*)(ws + 80744448);
  float* hstart = (float*)(ws + 81006592);

  convertW<<<dim3(512), dim3(256), 0, stream>>>(W_A, W_k, B_w, b_A, b_k,
                                                B_b, b_beta, Wb, bias);
  convertU<<<dim3(16384), dim3(256), 0, stream>>>(u, uh, ul);
  gemmA_mfma<<<dim3(128, 4), dim3(256), 0, stream>>>(uh, ul, Wb, Feat);
  convertC<<<dim3(128), dim3(256), 0, stream>>>(Cm, Chp, Clp);
  postA<<<dim3(16384), dim3(64), 0, stream>>>(Feat, bias, u, W_beta);
  scanB1<<<dim3(NCH), dim3(512), 0, stream>>>(Feat, Mc);
  scanB0<<<dim3(NCH), dim3(64), 0, stream>>>(Feat, dcv);
  scanB2<<<dim3(8), dim3(1024), 0, stream>>>(Mc, dcv, hstart);
  scanB3<<<dim3(NCH), dim3(64), 0, stream>>>(Feat, hstart, hsh, hsl);
  gemmC_mfma<<<dim3(128, 8), dim3(256), 0, stream>>>(hsh, hsl, Chp, Clp,
                                                     u, Dv, out);
}

// Round 10
// 394.643 us; speedup vs baseline: 1.2670x; 1.0057x over previous
//
#include <hip/hip_runtime.h>
#include <cmath>

// ---------------------------------------------------------------------------
// OHDeltaProductSSM: u(8,2048,1024) -> out(8,2048,1024), fp32.
// Round 10: T1 XCD-aware bijective block swizzle on gemmA and gemmC.
// R9 post-mortem: gemmA 60us, MfmaUtil 21%, VALUBusy 11% after deep
// pipeline -> not latency-bound; staging re-reads uh/ul 4x (one per
// col-tile) = ~268MB through L3 at ~4.5TB/s = the throttle. Swizzle puts
// all 4 col-tiles of a row-panel on ONE XCD (row-panel hits its L2 after
// first fetch): gemmA swz=(bid&7)*64+(bid>>3), row=swz>>2, col=swz&3;
// gemmC swz=(bid&7)*128+(bid>>3), row=swz>>3, col=swz&7. Pure index
// bijection -> zero correctness risk.
// Round 9 (kept): gemmA 4-buffer 3-ahead counted-vmcnt pipeline.
// Round 8 (kept): scanB2 reg-dbuf under bounds(1024,1); packW eliminated.
// Round 6 (kept): scanB1 round-2 shape; standalone scanB0. Round 3: LCH=32.
// Round 2: gemmC 3-pass split MFMA. Round 1: gemmA 2-pass split bf16 MFMA.
// Tiled operand layout: tile (rowblk, kt) = 128x32 bf16, 8 KB contiguous;
//   elem (r,k): g=k>>2, p=g&3, h=g>>2, s'=((p^((r>>2)&3))<<1)|h,
//   index = r*32 + s'*4 + (k&3); identical permutation on A and B.
// MFMA facts: A row = lane&15, B col = lane&15, D: col=lane&15,
// row = 4*(lane>>4)+reg  [guide m89/m91].
// ---------------------------------------------------------------------------

#define NTOK 16384
#define TT 2048
#define BB 8
#define DM 1024
#define FS 520
#define CH 64          // chunks per batch
#define LCH 32         // tokens per chunk
#define NCH 512        // total chunks
#define NW 448
#define NWP 512

typedef short bf16x8 __attribute__((ext_vector_type(8)));
typedef float f32x4 __attribute__((ext_vector_type(4)));

#define GLOAD_LDS16(g, l)                                          \
  __builtin_amdgcn_global_load_lds(                                \
      (const __attribute__((address_space(1))) void*)(g),          \
      (__attribute__((address_space(3))) void*)(l), 16, 0, 0)

// raw workgroup barrier that does NOT drain vmcnt (keeps global prefetches
// in flight). LDS ordering via lgkmcnt(0); sched_barrier fences both sides.
#define RAW_BAR() do {                                             \
    asm volatile("s_waitcnt lgkmcnt(0)" ::: "memory");             \
    __builtin_amdgcn_sched_barrier(0);                             \
    __builtin_amdgcn_s_barrier();                                  \
    __builtin_amdgcn_sched_barrier(0);                             \
  } while (0)

#define WAIT_VM(N) do {                                            \
    __builtin_amdgcn_sched_barrier(0);                             \
    asm volatile("s_waitcnt vmcnt(" #N ")" ::: "memory");          \
    __builtin_amdgcn_sched_barrier(0);                             \
  } while (0)

__device__ inline unsigned short bf16_rne(float x) {
  unsigned b = __float_as_uint(x);
  b += 0x7FFFu + ((b >> 16) & 1u);
  return (unsigned short)(b >> 16);
}

__device__ inline void split_bf16(float x, unsigned short& h, unsigned short& l) {
  unsigned b = __float_as_uint(x);
  h = (unsigned short)(b >> 16);                       // truncated high part
  float rem = x - __uint_as_float(b & 0xFFFF0000u);    // exact remainder
  l = bf16_rne(rem);
}

// u fp32 -> u_hi/u_lo bf16, tiled (mb,kt) 128x32, swizzled granules.
__global__ __launch_bounds__(256) void convertU(
    const float* __restrict__ u, unsigned short* __restrict__ uh,
    unsigned short* __restrict__ ul) {
  int gid = blockIdx.x * 256 + threadIdx.x;
  int m = gid >> 8;          // token row
  int g = gid & 255;         // granule along k
  float4 v = *(const float4*)(u + (size_t)m * DM + g * 4);
  int kt = g >> 3, gg = g & 7;
  int p = gg & 3, h = gg >> 2;
  int mr = m & 127, mb = m >> 7;
  int pp = p ^ ((mr >> 2) & 3);
  size_t dst = ((size_t)(mb * 32 + kt)) * 4096 + mr * 32 + ((pp << 1) | h) * 4;
  ushort4 hi, lo;
  split_bf16(v.x, hi.x, lo.x);
  split_bf16(v.y, hi.y, lo.y);
  split_bf16(v.z, hi.z, lo.z);
  split_bf16(v.w, hi.w, lo.w);
  *(ushort4*)(uh + dst) = hi;
  *(ushort4*)(ul + dst) = lo;
}

// weights -> Wb bf16 tiled (nb,kt) 128x32, rows 448..511 zero. Reads the
// original W_A/W_k/B_w directly (packW eliminated). Block 448 writes bias.
__global__ __launch_bounds__(256) void convertW(
    const float* __restrict__ W_A, const float* __restrict__ W_k,
    const float* __restrict__ B_w, const float* __restrict__ b_A,
    const float* __restrict__ b_k, const float* __restrict__ B_b,
    const float* __restrict__ b_beta, unsigned short* __restrict__ Wb,
    float* __restrict__ bias) {
  int n = blockIdx.x;        // 0..511 (row)
  int g = threadIdx.x;       // granule along k
  int kt = g >> 3, gg = g & 7;
  int p = gg & 3, h = gg >> 2;
  int nr = n & 127, nb = n >> 7;
  int pp = p ^ ((nr >> 2) & 3);
  size_t dst = ((size_t)(nb * 32 + kt)) * 4096 + nr * 32 + ((pp << 1) | h) * 4;
  ushort4 hv = make_ushort4(0, 0, 0, 0);
  if (n < NW) {
    const float* src;
    if (n < 64)       src = W_A + (size_t)n * DM;
    else if (n < 320) src = W_k + (size_t)(n - 64) * DM;
    else              src = B_w + (size_t)(n - 320) * DM;
    float4 v = *(const float4*)(src + g * 4);
    hv.x = bf16_rne(v.x); hv.y = bf16_rne(v.y);
    hv.z = bf16_rne(v.z); hv.w = bf16_rne(v.w);
  }
  *(ushort4*)(Wb + dst) = hv;
  if (n == 448) {
    for (int i = threadIdx.x; i < 450; i += 256) {
      float bv;
      if (i < 64)       bv = b_A[i];
      else if (i < 320) bv = b_k[i - 64];
      else if (i < 448) bv = B_b[i - 320];
      else              bv = b_beta[i - 448];
      bias[i] = bv;
    }
  }
}

// Cm[1024][128] fp32 -> C_hi/C_lo bf16 tiled (nb,kt).
__global__ __launch_bounds__(256) void convertC(
    const float* __restrict__ Cm, unsigned short* __restrict__ Chp,
    unsigned short* __restrict__ Clp) {
  int gid = blockIdx.x * 256 + threadIdx.x;   // 32768 total
  int d = gid >> 5;          // 0..1023
  int g = gid & 31;          // granule along 128
  float4 v = *(const float4*)(Cm + (size_t)d * 128 + g * 4);
  int kt = g >> 3, gg = g & 7;
  int p = gg & 3, h = gg >> 2;
  int nr = d & 127, nb = d >> 7;
  int pp = p ^ ((nr >> 2) & 3);
  size_t dst = ((size_t)(nb * 4 + kt)) * 4096 + nr * 32 + ((pp << 1) | h) * 4;
  ushort4 hi, lo;
  split_bf16(v.x, hi.x, lo.x);
  split_bf16(v.y, hi.y, lo.y);
  split_bf16(v.z, hi.z, lo.z);
  split_bf16(v.w, hi.w, lo.w);
  *(ushort4*)(Chp + dst) = hi;
  *(ushort4*)(Clp + dst) = lo;
}

// Feat[0..512) = (u_hi + u_lo) . Wb^T via MFMA. 128x128 tile, BK=32.
// 4-buffer, 3-ahead pipeline + XCD-chunked block swizzle (T1): XCD k owns
// row-tiles [16k,16k+16) with all 4 col-tiles -> uh/ul row-panels hit L2.
__global__ __launch_bounds__(256) void gemmA_mfma(
    const unsigned short* __restrict__ uh, const unsigned short* __restrict__ ul,
    const unsigned short* __restrict__ Wb, float* __restrict__ Feat) {
  __shared__ __align__(16) unsigned short As[4][4096];
  __shared__ __align__(16) unsigned short Bs[4][4096];
  const int bid = blockIdx.x;                  // 0..511
  const int swz = (bid & 7) * 64 + (bid >> 3); // bijective XCD chunking
  const int bx = swz >> 2, by = swz & 3;
  const int tid = threadIdx.x;
  const int wv = tid >> 6, ln = tid & 63;
  const int lr = ln & 15, G = ln >> 4;
  const int wm = wv >> 1, wn = wv & 1;
  const int x = G ^ (lr >> 2);
  f32x4 acc[4][4];
#pragma unroll
  for (int i = 0; i < 4; ++i)
#pragma unroll
    for (int j = 0; j < 4; ++j) acc[i][j] = (f32x4){0.f, 0.f, 0.f, 0.f};

  const size_t aBase = (size_t)bx * 32 * 4096;
  const size_t bBase = (size_t)by * 32 * 4096;
  const int so = wv * 512 + ln * 8;
  const int ld = wv * 512;

  auto stage = [&](int step) {
    const unsigned short* pa = (step < 32) ? uh : ul;
    const int kt = step & 31;
    const unsigned short* ga = pa + aBase + (size_t)kt * 4096;
    const unsigned short* gb = Wb + bBase + (size_t)kt * 4096;
    unsigned short* A = As[step & 3];
    unsigned short* B = Bs[step & 3];
    GLOAD_LDS16(ga + so,        A + ld);
    GLOAD_LDS16(ga + 2048 + so, A + 2048 + ld);
    GLOAD_LDS16(gb + so,        B + ld);
    GLOAD_LDS16(gb + 2048 + so, B + 2048 + ld);
  };

  stage(0); stage(1); stage(2);   // 12 vm outstanding
  WAIT_VM(8);                     // own stage(0) landed
  RAW_BAR();                      // all waves' stage(0) landed
  for (int s = 0; s < 64; ++s) {
    if (s + 3 < 64) stage(s + 3); // outstanding -> 12 (stages s+1,s+2,s+3)
    bf16x8 af[4], bfr[4];
    const char* Ab = (const char*)As[s & 3] + ((wm * 64 + lr) << 6) + (x << 4);
    const char* Bb = (const char*)Bs[s & 3] + ((wn * 64 + lr) << 6) + (x << 4);
#pragma unroll
    for (int i = 0; i < 4; ++i) {
      af[i]  = *(const bf16x8*)(Ab + i * 1024);
      bfr[i] = *(const bf16x8*)(Bb + i * 1024);
    }
#pragma unroll
    for (int i = 0; i < 4; ++i)
#pragma unroll
      for (int j = 0; j < 4; ++j)
        acc[i][j] = __builtin_amdgcn_mfma_f32_16x16x32_bf16(
            af[i], bfr[j], acc[i][j], 0, 0, 0);
    // drain stage(s+1) (read next iter); keep newer stages in flight
    if (s < 61)       WAIT_VM(8);
    else if (s == 61) WAIT_VM(4);
    else if (s == 62) WAIT_VM(0);
    RAW_BAR();
  }
  const int row0 = (bx << 7) + wm * 64 + (G << 2);
  const int col0 = (by << 7) + wn * 64 + lr;
  float* fb = Feat + (size_t)row0 * FS + col0;
#pragma unroll
  for (int i = 0; i < 4; ++i)
#pragma unroll
    for (int j = 0; j < 4; ++j) {
      float* d = fb + (size_t)(i * 16) * FS + j * 16;
#pragma unroll
      for (int r = 0; r < 4; ++r) d[(size_t)r * FS] = acc[i][j][r];
    }
}

// out = hs.C^T + u*D via MFMA, 3 passes (hh, lh, hl), 2-phase dbuf,
// XCD-chunked swizzle (T1): XCD k owns row-tiles [16k,16k+16) x 8 cols.
__global__ __launch_bounds__(256) void gemmC_mfma(
    const unsigned short* __restrict__ hsh, const unsigned short* __restrict__ hsl,
    const unsigned short* __restrict__ Chp, const unsigned short* __restrict__ Clp,
    const float* __restrict__ u, const float* __restrict__ Dv,
    float* __restrict__ out) {
  __shared__ __align__(16) unsigned short As[8192];
  __shared__ __align__(16) unsigned short Bs[8192];
  const int bid = blockIdx.x;                   // 0..1023
  const int swz = (bid & 7) * 128 + (bid >> 3); // bijective XCD chunking
  const int bx = swz >> 3, by = swz & 7;
  const int tid = threadIdx.x;
  const int wv = tid >> 6, ln = tid & 63;
  const int lr = ln & 15, G = ln >> 4;
  const int wm = wv >> 1, wn = wv & 1;
  const int x = G ^ (lr >> 2);
  f32x4 acc[4][4];
#pragma unroll
  for (int i = 0; i < 4; ++i)
#pragma unroll
    for (int j = 0; j < 4; ++j) acc[i][j] = (f32x4){0.f, 0.f, 0.f, 0.f};

  const size_t aBase = (size_t)bx * 4 * 4096;
  const size_t bBase = (size_t)by * 4 * 4096;
  const int so = wv * 512 + ln * 8;
  const int ld = wv * 512;

  auto stage = [&](int step, int buf) {
    const int pass = step >> 2, kt = step & 3;
    const unsigned short* pa = (pass == 1) ? hsl : hsh;
    const unsigned short* pb = (pass == 2) ? Clp : Chp;
    const unsigned short* ga = pa + aBase + (size_t)kt * 4096;
    const unsigned short* gb = pb + bBase + (size_t)kt * 4096;
    unsigned short* A = As + buf * 4096;
    unsigned short* B = Bs + buf * 4096;
    GLOAD_LDS16(ga + so,        A + ld);
    GLOAD_LDS16(ga + 2048 + so, A + 2048 + ld);
    GLOAD_LDS16(gb + so,        B + ld);
    GLOAD_LDS16(gb + 2048 + so, B + 2048 + ld);
  };

  stage(0, 0);
  __syncthreads();
  for (int s = 0; s < 12; ++s) {
    const int cur = s & 1;
    if (s + 1 < 12) stage(s + 1, cur ^ 1);
    bf16x8 af[4], bfr[4];
    const char* Ab = (const char*)(As + cur * 4096) + ((wm * 64 + lr) << 6) + (x << 4);
    const char* Bb = (const char*)(Bs + cur * 4096) + ((wn * 64 + lr) << 6) + (x << 4);
#pragma unroll
    for (int i = 0; i < 4; ++i) {
      af[i]  = *(const bf16x8*)(Ab + i * 1024);
      bfr[i] = *(const bf16x8*)(Bb + i * 1024);
    }
#pragma unroll
    for (int i = 0; i < 4; ++i)
#pragma unroll
      for (int j = 0; j < 4; ++j)
        acc[i][j] = __builtin_amdgcn_mfma_f32_16x16x32_bf16(
            af[i], bfr[j], acc[i][j], 0, 0, 0);
    __syncthreads();
  }
  const int row0 = (bx << 7) + wm * 64 + (G << 2);
  const int col0 = (by << 7) + wn * 64 + lr;
#pragma unroll
  for (int j = 0; j < 4; ++j) {
    float dv = Dv[col0 + j * 16];
#pragma unroll
    for (int i = 0; i < 4; ++i) {
#pragma unroll
      for (int r = 0; r < 4; ++r) {
        size_t off = (size_t)(row0 + i * 16 + r) * DM + col0 + j * 16;
        out[off] = fmaf(u[off], dv, acc[i][j][r]);
      }
    }
  }
}

__device__ inline float wave_sum(float v) {
#pragma unroll
  for (int off = 32; off > 0; off >>= 1) v += __shfl_xor(v, off, 64);
  return v;
}

// per-token nonlinearity, one wave per token, in-place in Feat
__global__ __launch_bounds__(64) void postA(float* __restrict__ Feat,
                                            const float* __restrict__ bias,
                                            const float* __restrict__ u,
                                            const float* __restrict__ Wb) {
  const int t = blockIdx.x, lane = threadIdx.x;
  float* f = Feat + (size_t)t * FS;
  float s0 = 0.f, s1 = 0.f;
#pragma unroll
  for (int j = 0; j < 4; ++j) {
    float4 uv = *(const float4*)(u + (size_t)t * DM + j * 256 + lane * 4);
    float4 w0 = *(const float4*)(Wb + j * 256 + lane * 4);
    float4 w1 = *(const float4*)(Wb + DM + j * 256 + lane * 4);
    s0 = fmaf(uv.x, w0.x, s0); s0 = fmaf(uv.y, w0.y, s0);
    s0 = fmaf(uv.z, w0.z, s0); s0 = fmaf(uv.w, w0.w, s0);
    s1 = fmaf(uv.x, w1.x, s1); s1 = fmaf(uv.y, w1.y, s1);
    s1 = fmaf(uv.z, w1.z, s1); s1 = fmaf(uv.w, w1.w, s1);
  }
  s0 = wave_sum(s0); s1 = wave_sum(s1);
  float a = f[lane] + bias[lane];
  a = fminf(fmaxf(a, 0.f), 100.f);
  float S = 1.f / (1.f + 0.01f * a);
  f[lane] = S;
  f[448 + lane] = 0.1f * a * S;
  float k10 = f[64 + lane] + bias[64 + lane];
  float k11 = f[128 + lane] + bias[128 + lane];
  float n1 = wave_sum(k10 * k10 + k11 * k11);
  float inv1 = 1.f / fmaxf(sqrtf(n1), 1e-12f);
  k10 *= inv1; k11 *= inv1;
  f[64 + lane] = k10; f[128 + lane] = k11;
  float k20 = f[192 + lane] + bias[192 + lane];
  float k21 = f[256 + lane] + bias[256 + lane];
  float n2 = wave_sum(k20 * k20 + k21 * k21);
  float inv2 = 1.f / fmaxf(sqrtf(n2), 1e-12f);
  k20 *= inv2; k21 *= inv2;
  f[192 + lane] = k20; f[256 + lane] = k21;
  float c12 = wave_sum(k10 * k20 + k11 * k21);
  if (lane == 0) {
    f[512] = 2.f / (1.f + expf(-(s0 + bias[448])));
    f[513] = 2.f / (1.f + expf(-(s1 + bias[449])));
    f[514] = c12;
  }
  f[320 + lane] += bias[320 + lane];
  f[384 + lane] += bias[384 + lane];
}

// chunk transition matrices. Round-2-verified shape: 512 threads,
// col = tid>>2 (0..127), quarter q = tid&3, 16 elems/thread, VGPR=64.
__global__ __launch_bounds__(512, 2) void scanB1(
    const float* __restrict__ Feat, float* __restrict__ Mc) {
  const int cid = blockIdx.x;              // 0..511 = b*64 + chunk
  const int t0 = (cid >> 6) * TT + (cid & 63) * LCH;
  const int tid = threadIdx.x;
  const int col = tid >> 2, q = tid & 3;
  const int i0 = q * 16;
  __shared__ float fb[2][4 * FS];
  float mz[16], my[16];
#pragma unroll
  for (int j = 0; j < 16; ++j) {
    mz[j] = (i0 + j == col) ? 1.f : 0.f;
    my[j] = (64 + i0 + j == col) ? 1.f : 0.f;
  }
  {
    const float4* src = (const float4*)(Feat + (size_t)t0 * FS);
    for (int v = tid; v < FS; v += 512) ((float4*)fb[0])[v] = src[v];
  }
  __syncthreads();
  for (int g = 0; g < LCH / 4; ++g) {
    const int cur = g & 1;
    float4 pf0, pf1;
    const bool has2 = tid < (FS - 512);
    if (g < LCH / 4 - 1) {
      const float4* src = (const float4*)(Feat + (size_t)(t0 + (g + 1) * 4) * FS);
      pf0 = src[tid];
      if (has2) pf1 = src[tid + 512];
    }
#pragma unroll
    for (int s = 0; s < 4; ++s) {
      const float* f = fb[cur] + s * FS;
      float sj[16], cj[16], k1z[16], k1y[16], k2z[16], k2y[16];
#pragma unroll
      for (int v = 0; v < 4; ++v) {
        *(float4*)&sj[4 * v]  = *(const float4*)(f + i0 + 4 * v);
        *(float4*)&cj[4 * v]  = *(const float4*)(f + 448 + i0 + 4 * v);
        *(float4*)&k1z[4 * v] = *(const float4*)(f + 64 + i0 + 4 * v);
        *(float4*)&k1y[4 * v] = *(const float4*)(f + 128 + i0 + 4 * v);
        *(float4*)&k2z[4 * v] = *(const float4*)(f + 192 + i0 + 4 * v);
        *(float4*)&k2y[4 * v] = *(const float4*)(f + 256 + i0 + 4 * v);
      }
      float4 sc = *(const float4*)(f + 512);   // b1, b2, c12, pad
      float p = 0.f, r2 = 0.f;
#pragma unroll
      for (int j = 0; j < 16; ++j) {
        float s0 = sj[j], c1 = cj[j];
        float z = mz[j], y = my[j];
        float sz = s0 * z;
        z = fmaf(-c1, y, sz);
        y = fmaf(s0, y, 0.1f * sz);
        mz[j] = z; my[j] = y;
        p  = fmaf(k1z[j], z, p);  p  = fmaf(k1y[j], y, p);
        r2 = fmaf(k2z[j], z, r2); r2 = fmaf(k2y[j], y, r2);
      }
      p  += __shfl_xor(p, 1, 64);  p  += __shfl_xor(p, 2, 64);
      r2 += __shfl_xor(r2, 1, 64); r2 += __shfl_xor(r2, 2, 64);
      float e1 = sc.x * p;
      float e2 = sc.y * fmaf(-sc.z, e1, r2);
#pragma unroll
      for (int j = 0; j < 16; ++j) {
        float z = fmaf(-e1, k1z[j], mz[j]);
        mz[j] = fmaf(-e2, k2z[j], z);
        float y = fmaf(-e1, k1y[j], my[j]);
        my[j] = fmaf(-e2, k2y[j], y);
      }
    }
    if (g < LCH / 4 - 1) {
      ((float4*)fb[1 - cur])[tid] = pf0;
      if (has2) ((float4*)fb[1 - cur])[tid + 512] = pf1;
    }
    __syncthreads();
  }
  float* dst = Mc + ((size_t)cid * 128 + col) * 128;
#pragma unroll
  for (int v = 0; v < 4; ++v)
    *(float4*)(dst + i0 + 4 * v) = *(float4*)&mz[4 * v];
#pragma unroll
  for (int v = 0; v < 4; ++v)
    *(float4*)(dst + 64 + i0 + 4 * v) = *(float4*)&my[4 * v];
}

// offset column d_c: affine replay from h=0, one wave per chunk
__global__ __launch_bounds__(64) void scanB0(
    const float* __restrict__ Feat, float* __restrict__ dc) {
  const int cid = blockIdx.x;
  const int lane = threadIdx.x;
  float z = 0.f, y = 0.f;
  const int t0 = (cid >> 6) * TT + (cid & 63) * LCH;
  for (int t = t0; t < t0 + LCH; ++t) {
    const float* __restrict__ f = Feat + (size_t)t * FS;
    float s = f[lane], c1 = f[448 + lane];
    float k1z = f[64 + lane], k1y = f[128 + lane];
    float k2z = f[192 + lane], k2y = f[256 + lane];
    float bz = f[320 + lane], by = f[384 + lane];
    float b1 = f[512], b2 = f[513], c12 = f[514];
    float sz = s * z;
    float zn = fmaf(-c1, y, sz);
    float yn = fmaf(s, y, 0.1f * sz);
    float p = fmaf(k1y, yn, k1z * zn);
    float qq = fmaf(k2y, yn, k2z * zn);
#pragma unroll
    for (int off = 32; off > 0; off >>= 1) {
      p += __shfl_xor(p, off, 64);
      qq += __shfl_xor(qq, off, 64);
    }
    float e1 = b1 * p;
    float d2 = fmaf(-c12, e1, qq);
    float e2 = b2 * d2;
    z = fmaf(-e1, k1z, zn); z = fmaf(-e2, k2z, z); z += bz;
    y = fmaf(-e1, k1y, yn); y = fmaf(-e2, k2y, y); y += by;
  }
  dc[(size_t)cid * 128 + lane] = z;
  dc[(size_t)cid * 128 + 64 + lane] = y;
}

// sequential chunk combine: h <- M_c h + d_c, store h at chunk starts.
// 1024 threads: i = tid&127, jh = tid>>7. Register double-buffer prefetch
// (ma/mb + d0/d1) under bounds(1024,1) (no VGPR cap -> no spill, cf. R4);
// raw lgkm-only barriers keep the prefetch in flight across the iteration.
__global__ __launch_bounds__(1024, 1) void scanB2(
    const float* __restrict__ Mc, const float* __restrict__ dc,
    float* __restrict__ hstart) {
  const int b = blockIdx.x;
  const int tid = threadIdx.x;
  const int i = tid & 127, jh = tid >> 7;   // jh 0..7
  __shared__ float h[128];
  __shared__ float red[8][128];
  if (tid < 128) h[tid] = 0.f;
  __syncthreads();
  float ma[16], mb[16];
  float d0, d1;
  {
    const float* M0 = Mc + (size_t)(b * CH) * 16384;
#pragma unroll
    for (int j = 0; j < 16; ++j) ma[j] = M0[(size_t)(jh * 16 + j) * 128 + i];
    d0 = dc[(size_t)(b * CH) * 128 + i];
  }
  for (int c = 0; c < CH; ++c) {
    // prefetch next chunk's M and d; waitcnt lands at the ma=mb copy after
    // the 2nd barrier -> a full iteration of latency cover, never drained.
    const int cn = (c + 1 < CH) ? c + 1 : c;
    const float* Mn = Mc + (size_t)(b * CH + cn) * 16384;
#pragma unroll
    for (int j = 0; j < 16; ++j) mb[j] = Mn[(size_t)(jh * 16 + j) * 128 + i];
    d1 = dc[(size_t)(b * CH + cn) * 128 + i];
    if (tid < 128) hstart[(size_t)(b * CH + c) * 128 + tid] = h[tid];
    float acc = 0.f;
#pragma unroll
    for (int j = 0; j < 16; ++j) acc = fmaf(ma[j], h[jh * 16 + j], acc);
    red[jh][i] = acc;
    RAW_BAR();
    if (tid < 128) {
      float sum = d0;
#pragma unroll
      for (int k = 0; k < 8; ++k) sum += red[k][tid];
      h[tid] = sum;
    }
    RAW_BAR();
#pragma unroll
    for (int j = 0; j < 16; ++j) ma[j] = mb[j];
    d0 = d1;
  }
}

// replay within chunk from h_start, one wave per chunk; write split bf16 hs
// in the tiled swizzled layout for gemmC_mfma.
__global__ __launch_bounds__(64) void scanB3(
    const float* __restrict__ Feat, const float* __restrict__ hstart,
    unsigned short* __restrict__ hsh, unsigned short* __restrict__ hsl) {
  const int cid = blockIdx.x;
  const int lane = threadIdx.x;
  float z = hstart[(size_t)cid * 128 + lane];
  float y = hstart[(size_t)cid * 128 + 64 + lane];
  const int t0 = (cid >> 6) * TT + (cid & 63) * LCH;
  const int ktz = lane >> 5, kkz = lane & 31;
  const int kty = (64 + lane) >> 5;
  const int pz = (kkz >> 2) & 3, hz = kkz >> 4;
  const int lowz = kkz & 3;
  for (int t = t0; t < t0 + LCH; ++t) {
    const float* __restrict__ f = Feat + (size_t)t * FS;
    float s = f[lane], c1 = f[448 + lane];
    float k1z = f[64 + lane], k1y = f[128 + lane];
    float k2z = f[192 + lane], k2y = f[256 + lane];
    float bz = f[320 + lane], by = f[384 + lane];
    float b1 = f[512], b2 = f[513], c12 = f[514];
    float sz = s * z;
    float zn = fmaf(-c1, y, sz);
    float yn = fmaf(s, y, 0.1f * sz);
    float p = fmaf(k1y, yn, k1z * zn);
    float qq = fmaf(k2y, yn, k2z * zn);
#pragma unroll
    for (int off = 32; off > 0; off >>= 1) {
      p += __shfl_xor(p, off, 64);
      qq += __shfl_xor(qq, off, 64);
    }
    float e1 = b1 * p;
    float d2 = fmaf(-c12, e1, qq);
    float e2 = b2 * d2;
    zn = fmaf(-e1, k1z, zn); zn = fmaf(-e2, k2z, zn); zn += bz;
    yn = fmaf(-e1, k1y, yn); yn = fmaf(-e2, k2y, yn); yn += by;
    {
      const int mb = t >> 7, mr = t & 127;
      const int xr = (mr >> 2) & 3;
      size_t idxz = ((size_t)(mb * 4 + ktz)) * 4096 + mr * 32 +
                    ((((pz ^ xr) << 1) | hz)) * 4 + lowz;
      size_t idxy = ((size_t)(mb * 4 + kty)) * 4096 + mr * 32 +
                    ((((pz ^ xr) << 1) | hz)) * 4 + lowz;
      unsigned short hi, lo;
      split_bf16(zn, hi, lo);
      hsh[idxz] = hi; hsl[idxz] = lo;
      split_bf16(yn, hi, lo);
      hsh[idxy] = hi; hsl[idxy] = lo;
    }
    z = zn; y = yn;
  }
}

extern "C" void kernel_launch(void* const* d_in, const int* in_sizes, int n_in,
                              void* d_out, int out_size, void* d_ws, size_t ws_size,
                              hipStream_t stream) {
  const float* u      = (const float*)d_in[0];
  const float* W_A    = (const float*)d_in[1];
  const float* b_A    = (const float*)d_in[2];
  const float* W_k    = (const float*)d_in[3];
  const float* b_k    = (const float*)d_in[4];
  const float* W_beta = (const float*)d_in[5];
  const float* b_beta = (const float*)d_in[6];
  const float* B_w    = (const float*)d_in[7];
  const float* B_b    = (const float*)d_in[8];
  const float* Cm     = (const float*)d_in[9];
  const float* Dv     = (const float*)d_in[10];
  float* out = (float*)d_out;
  char* ws = (char*)d_ws;
  // workspace carve-up (~105.4 MB):
  //  Wb    1,835,008  1,048,576
  //  bias  4,194,304  4,096
  //  Feat  4,198,400  34,078,720           -> ends 38,277,120
  //  uh    38,277,120 33,554,432  [dead after gemmA]
  //  Mc    38,277,120 33,554,432  (512*128*128*4, overlays uh)
  //  ul    71,831,552 33,554,432  [dead after gemmA pass 2]
  //   hsh  71,831,552 4,194,304   (overlays ul)
  //   hsl  76,025,856 4,194,304
  //   Chp  80,220,160 262,144
  //   Clp  80,482,304 262,144
  //   dcv  80,744,448 262,144
  //   hst  81,006,592 262,144     -> ends 81,268,736 (< ul end)
  unsigned short* Wb = (unsigned short*)(ws + 1835008);
  float* bias   = (float*)(ws + 4194304);
  float* Feat   = (float*)(ws + 4198400);
  unsigned short* uh = (unsigned short*)(ws + 38277120);
  float* Mc     = (float*)(ws + 38277120);
  unsigned short* ul = (unsigned short*)(ws + 71831552);
  unsigned short* hsh = (unsigned short*)(ws + 71831552);
  unsigned short* hsl = (unsigned short*)(ws + 76025856);
  unsigned short* Chp = (unsigned short*)(ws + 80220160);
  unsigned short* Clp = (unsigned short*)(ws + 80482304);
  float* dcv    = (float*)(ws + 80744448);
  float* hstart = (float*)(ws + 81006592);

  convertW<<<dim3(512), dim3(256), 0, stream>>>(W_A, W_k, B_w, b_A, b_k,
                                                B_b, b_beta, Wb, bias);
  convertU<<<dim3(16384), dim3(256), 0, stream>>>(u, uh, ul);
  gemmA_mfma<<<dim3(512), dim3(256), 0, stream>>>(uh, ul, Wb, Feat);
  convertC<<<dim3(128), dim3(256), 0, stream>>>(Cm, Chp, Clp);
  postA<<<dim3(16384), dim3(64), 0, stream>>>(Feat, bias, u, W_beta);
  scanB1<<<dim3(NCH), dim3(512), 0, stream>>>(Feat, Mc);
  scanB0<<<dim3(NCH), dim3(64), 0, stream>>>(Feat, dcv);
  scanB2<<<dim3(8), dim3(1024), 0, stream>>>(Mc, dcv, hstart);
  scanB3<<<dim3(NCH), dim3(64), 0, stream>>>(Feat, hstart, hsh, hsl);
  gemmC_mfma<<<dim3(1024), dim3(256), 0, stream>>>(hsh, hsl, Chp, Clp,
                                                   u, Dv, out);
}